// Round 3
// baseline (1607.186 us; speedup 1.0000x reference)
//
#include <hip/hip_runtime.h>

#define L_HIST 2048
typedef unsigned short ushortT;
typedef __attribute__((ext_vector_type(8))) short bf16x8;
typedef __attribute__((ext_vector_type(4))) short bf16x4;
typedef __attribute__((ext_vector_type(16))) float f32x16;

__device__ __forceinline__ ushortT f2bf(float x) {
  union { float f; unsigned u; } v; v.f = x;
  unsigned r = (v.u + 0x7FFFu + ((v.u >> 16) & 1u)) >> 16;
  return (ushortT)r;
}
__device__ __forceinline__ float bf2f(ushortT h) {
  union { unsigned u; float f; } v; v.u = ((unsigned)h) << 16; return v.f;
}
__device__ __forceinline__ bf16x4 lo4(bf16x8 v) {
  return __builtin_shufflevector(v, v, 0, 1, 2, 3);
}
__device__ __forceinline__ bf16x4 hi4(bf16x8 v) {
  return __builtin_shufflevector(v, v, 4, 5, 6, 7);
}
__device__ __forceinline__ bf16x8 rd8(const ushortT* p) {
  bf16x4 a = *(const bf16x4*)p, b = *(const bf16x4*)(p + 4);
  return __builtin_shufflevector(a, b, 0, 1, 2, 3, 4, 5, 6, 7);
}

// ---------------- persistent mega-chain kernel -------------------------------
// 13 steps separated by device-scope grid barriers. Per step, item ranges:
// [0,qbase) GEMM-job tiles | [qbase,rbase) qgemm | [rbase,sbase) rgemm |
// [sbase,fbase) sgemm | [fbase,utbase) finalize | [utbase,W) ut_gemv slices.
struct Job {
  const ushortT *Ph, *Qh, *Ql;
  ushortT *Ch, *Cl;
  float *Cf;
  int M, tbase;
};
struct Step { int jbase, nj, qbase, rbase, sbase, fbase, utbase, W, ut0; };
struct Prm {
  Job jobs[27];
  Step st[13];
  const ushortT *Wt, *Uh, *Ul;
  float *Qp, *Rp, *Sp;
  const float *Pf1, *Pf2, *Mt, *Mbar, *wv, *Cmat, *yh;
  float *outp;
  unsigned *bar;
  int nsteps, nblocks;
};

// sense-reversal grid barrier; all blocks guaranteed co-resident (grid=256,
// LDS 110KB -> exactly 1 block/CU on 256 CUs). Agent scope for cross-XCD.
__device__ __forceinline__ void gridbar(unsigned* bar, int nb) {
  __syncthreads();
  if (threadIdx.x == 0) {
    __threadfence();
    unsigned g = __hip_atomic_load(&bar[1], __ATOMIC_RELAXED, __HIP_MEMORY_SCOPE_AGENT);
    unsigned old = __hip_atomic_fetch_add(&bar[0], 1u, __ATOMIC_ACQ_REL, __HIP_MEMORY_SCOPE_AGENT);
    if (old == (unsigned)(nb - 1)) {
      __hip_atomic_store(&bar[0], 0u, __ATOMIC_RELAXED, __HIP_MEMORY_SCOPE_AGENT);
      __hip_atomic_fetch_add(&bar[1], 1u, __ATOMIC_RELEASE, __HIP_MEMORY_SCOPE_AGENT);
    } else {
      while (__hip_atomic_load(&bar[1], __ATOMIC_ACQUIRE, __HIP_MEMORY_SCOPE_AGENT) == g)
        __builtin_amdgcn_s_sleep(2);
    }
  }
  __syncthreads();
}

__global__ __launch_bounds__(256) void megachain(Prm p) {
  __shared__ __align__(16) ushortT As[4][64][36];
  __shared__ ushortT Bhs[4][64][36];
  __shared__ ushortT Bls[4][64][36];
  int tid = threadIdx.x;
  int lane = tid & 63, wave = tid >> 6;
  int wm = (wave & 1) * 32, wn = (wave >> 1) * 32;
  int fr = lane & 31, fk = (lane >> 5) * 8;

  for (int s = 0; s < p.nsteps; ++s) {
    Step st = p.st[s];
    for (int i = blockIdx.x; i < st.W; i += p.nblocks) {
      if (i >= st.utbase) {
        // ---- u_t gemv slice ----
        int u = i - st.utbase + st.ut0;
        int n = u & 255, h = u >> 8;
        int wid = wave;
        int vs = (306 * h) >> 2, ve = (306 * (h + 1)) >> 2;
        float4 acc = {0.f, 0.f, 0.f, 0.f};
#pragma unroll 4
        for (int v = vs + wid; v < ve; v += 4) {
          const float* mat = (v < 17 ? p.Mbar : p.Mt - 17 * 65536) + (size_t)v * 65536;
          float4 mv = ((const float4*)(mat + (size_t)n * 256))[lane];
          float4 wv = ((const float4*)(p.wv + (size_t)v * 256))[lane];
          acc.x += mv.x * wv.x; acc.y += mv.y * wv.y;
          acc.z += mv.z * wv.z; acc.w += mv.w * wv.w;
        }
        float a = (acc.x + acc.y) + (acc.z + acc.w);
        for (int off = 32; off > 0; off >>= 1) a += __shfl_down(a, off);
        if (lane == 0) atomicAdd(&p.outp[512 + n], a);
      } else if (i >= st.fbase) {
        // ---- finalize: 4 p's per item, one per wave ----
        int f = i - st.fbase;
        int pidx = f * 4 + wave;
        float a1 = 0.f, a2 = 0.f;
        for (int t = lane; t < 512; t += 64) {
          float sb = 0.f, qp = 0.f;
#pragma unroll
          for (int z = 0; z < 16; ++z) {
            sb += p.Qp[((size_t)z * 512 + t) * 128 + 0];
            qp += p.Qp[((size_t)z * 512 + t) * 128 + 64];
          }
          for (int q = 0; q < 28; ++q) {
            sb += p.Rp[(size_t)q * 4096 + t * 8];
            sb += p.Sp[(size_t)q * 512 + t];
          }
          float cv = p.Cmat[(size_t)pidx * 512 + t];
          a1 += cv * sb;
          a2 += cv * qp;
        }
        for (int off = 32; off > 0; off >>= 1) {
          a1 += __shfl_down(a1, off);
          a2 += __shfl_down(a2, off);
        }
        if (lane == 0) {
          float ynat = p.yh[(size_t)(L_HIST - 1) * 256 + pidx] - a1;
          p.outp[pidx] = ynat;
          p.outp[256 + pidx] = ynat + a2;
        }
      } else if (i >= st.sbase) {
        // ---- S partials (256-thread halves) ----
        int s2 = i - st.sbase;              // 0..55
        int j2 = (s2 >> 3) + 1;
        int rem = s2 & 7;
        int dc = rem >> 1, mh = rem & 1;
        int d0 = dc * 128, m = mh * 256 + tid;
        float* Rs = (float*)&As[0][0][0];
        if (tid < 128) {
          int dd = tid;
          float sv = 0.f;
#pragma unroll
          for (int z = 0; z < 16; ++z)
            sv += p.Qp[((size_t)z * 512 + d0 + dd) * 128 + 8 * j2];
          for (int q = 0; q < 28; ++q)
            sv += p.Rp[(size_t)q * 4096 + (d0 + dd) * 8 + j2];
          Rs[dd] = sv;
        }
        __syncthreads();
        float acc = 0.f;
        for (int d = 0; d < 128; ++d)
          acc += p.Pf2[((size_t)(j2 - 1) * 512 + d0 + d) * 512 + m] * Rs[d];
        p.Sp[(size_t)((j2 - 1) * 4 + dc) * 512 + m] = acc;
      } else if (i >= st.rbase) {
        // ---- R partials (256-thread halves) ----
        int r = i - st.rbase;
        float* Qs = (float*)&As[0][0][0];   // [128][8] fp32
        int pr = r >> 1, mh = r & 1;
        int j1 = (pr >> 2) + 1, dc = pr & 3;
        int d0 = dc * 128, m = mh * 256 + tid;
        for (int e = tid; e < 1024; e += 256) {
          int dd = e >> 3, jj = e & 7;
          float sv = 0.f;
#pragma unroll
          for (int z = 0; z < 16; ++z)
            sv += p.Qp[((size_t)z * 512 + d0 + dd) * 128 + j1 + 8 * jj];
          Qs[dd * 8 + jj] = sv;
        }
        __syncthreads();
        float acc[8];
#pragma unroll
        for (int jj = 0; jj < 8; ++jj) acc[jj] = 0.f;
        for (int d = 0; d < 128; ++d) {
          float tv = p.Pf1[((size_t)(j1 - 1) * 512 + d0 + d) * 512 + m];
          float4 q0 = *(const float4*)&Qs[d * 8];
          float4 q1 = *(const float4*)&Qs[d * 8 + 4];
          acc[0] += tv * q0.x; acc[1] += tv * q0.y; acc[2] += tv * q0.z; acc[3] += tv * q0.w;
          acc[4] += tv * q1.x; acc[5] += tv * q1.y; acc[6] += tv * q1.z; acc[7] += tv * q1.w;
        }
        float* dst = p.Rp + (size_t)((j1 - 1) * 4 + dc) * 4096 + m * 8;
#pragma unroll
        for (int jj = 0; jj < 8; ++jj) dst[jj] = acc[jj];
      } else if (i >= st.qbase) {
        // ---- Q = W*U, z-split 16 ----
        int q = i - st.qbase;
        int z = q & 15, mtile = (q >> 4) & 7, ntile = q >> 7;
        int m0 = mtile * 64, n0 = ntile * 64, k0 = z * 512;
        int ka = tid & 31, ma = (tid >> 5) * 8;
        int jb = tid >> 2, kb = (tid & 3) * 8;

        const ushortT* pW  = p.Wt + (size_t)(k0 + ka) * 512 + m0 + ma;
        const ushortT* pUh = p.Uh + (size_t)(n0 + jb) * 8192 + k0 + kb;
        const ushortT* pUl = p.Ul + (size_t)(n0 + jb) * 8192 + k0 + kb;

        bf16x8 rW[4], rUh[4], rUl[4];
#pragma unroll
        for (int t = 0; t < 4; ++t) {
          rW[t]  = *(const bf16x8*)(pW + (size_t)(t * 32) * 512);
          rUh[t] = *(const bf16x8*)(pUh + t * 32);
          rUl[t] = *(const bf16x8*)(pUl + t * 32);
        }
        f32x16 acc;
#pragma unroll
        for (int t = 0; t < 16; ++t) acc[t] = 0.f;

        for (int c = 0; c < 4; ++c) {
#pragma unroll
          for (int t = 0; t < 4; ++t) {
#pragma unroll
            for (int e = 0; e < 8; ++e) As[t][ma + e][ka] = (ushortT)rW[t][e];
            *(bf16x4*)&Bhs[t][jb][kb]     = lo4(rUh[t]);
            *(bf16x4*)&Bhs[t][jb][kb + 4] = hi4(rUh[t]);
            *(bf16x4*)&Bls[t][jb][kb]     = lo4(rUl[t]);
            *(bf16x4*)&Bls[t][jb][kb + 4] = hi4(rUl[t]);
          }
          __syncthreads();
          if (c < 3) {
            int off = (c + 1) * 128;
#pragma unroll
            for (int t = 0; t < 4; ++t) {
              rW[t]  = *(const bf16x8*)(pW + (size_t)(off + t * 32) * 512);
              rUh[t] = *(const bf16x8*)(pUh + off + t * 32);
              rUl[t] = *(const bf16x8*)(pUl + off + t * 32);
            }
          }
#pragma unroll
          for (int t = 0; t < 4; ++t)
#pragma unroll
            for (int ks = 0; ks < 32; ks += 16) {
              bf16x8 a  = rd8(&As[t][wm + fr][ks + fk]);
              bf16x8 bh = rd8(&Bhs[t][wn + fr][ks + fk]);
              bf16x8 bl = rd8(&Bls[t][wn + fr][ks + fk]);
              acc = __builtin_amdgcn_mfma_f32_32x32x16_bf16(a, bh, acc, 0, 0, 0);
              acc = __builtin_amdgcn_mfma_f32_32x32x16_bf16(a, bl, acc, 0, 0, 0);
            }
          __syncthreads();
        }
#pragma unroll
        for (int t = 0; t < 16; ++t) {
          int rr = wm + (t & 3) + ((t >> 2) << 3) + ((lane >> 5) << 2);
          int cc = wn + (lane & 31);
          p.Qp[((size_t)z * 512 + m0 + rr) * 128 + n0 + cc] = acc[t];
        }
      } else {
        // ---- dual-product bf16 bt-GEMM tile ----
        int ji = 0;
        for (int t = 1; t < st.nj; ++t)
          if (i >= p.jobs[st.jbase + t].tbase) ji = t;
        Job J = p.jobs[st.jbase + ji];
        int lt = i - J.tbase;
        int mt = J.M >> 6;
        int mtile = lt % mt, ntile = lt / mt;
        size_t m0 = (size_t)mtile * 64, n0 = (size_t)ntile * 64;
        int row = tid >> 2, kp = (tid & 3) * 8;

        const ushortT* pA  = J.Ph + (m0 + row) * 512 + kp;
        const ushortT* pBh = J.Qh + (n0 + row) * 512 + kp;
        const ushortT* pBl = J.Ql + (n0 + row) * 512 + kp;

        bf16x8 rA[4], rBh[4], rBl[4];
#pragma unroll
        for (int t = 0; t < 4; ++t) {
          rA[t]  = *(const bf16x8*)(pA  + t * 32);
          rBh[t] = *(const bf16x8*)(pBh + t * 32);
          rBl[t] = *(const bf16x8*)(pBl + t * 32);
        }
        f32x16 acc;
#pragma unroll
        for (int t = 0; t < 16; ++t) acc[t] = 0.f;

        for (int c = 0; c < 4; ++c) {
#pragma unroll
          for (int t = 0; t < 4; ++t) {
            *(bf16x4*)&As[t][row][kp]       = lo4(rA[t]);
            *(bf16x4*)&As[t][row][kp + 4]   = hi4(rA[t]);
            *(bf16x4*)&Bhs[t][row][kp]      = lo4(rBh[t]);
            *(bf16x4*)&Bhs[t][row][kp + 4]  = hi4(rBh[t]);
            *(bf16x4*)&Bls[t][row][kp]      = lo4(rBl[t]);
            *(bf16x4*)&Bls[t][row][kp + 4]  = hi4(rBl[t]);
          }
          __syncthreads();
          if (c < 3) {
            int off = (c + 1) * 128;
#pragma unroll
            for (int t = 0; t < 4; ++t) {
              rA[t]  = *(const bf16x8*)(pA  + off + t * 32);
              rBh[t] = *(const bf16x8*)(pBh + off + t * 32);
              rBl[t] = *(const bf16x8*)(pBl + off + t * 32);
            }
          }
#pragma unroll
          for (int t = 0; t < 4; ++t)
#pragma unroll
            for (int ks = 0; ks < 32; ks += 16) {
              bf16x8 a  = rd8(&As[t][wm + fr][ks + fk]);
              bf16x8 bh = rd8(&Bhs[t][wn + fr][ks + fk]);
              bf16x8 bl = rd8(&Bls[t][wn + fr][ks + fk]);
              acc = __builtin_amdgcn_mfma_f32_32x32x16_bf16(a, bh, acc, 0, 0, 0);
              acc = __builtin_amdgcn_mfma_f32_32x32x16_bf16(a, bl, acc, 0, 0, 0);
            }
          __syncthreads();
        }
#pragma unroll
        for (int t = 0; t < 16; ++t) {
          int rr = wm + (t & 3) + ((t >> 2) << 3) + ((lane >> 5) << 2);
          int cc = wn + (lane & 31);
          float v = acc[t];
          size_t off = (m0 + rr) * 512 + (n0 + cc);
          ushortT h = f2bf(v);
          J.Ch[off] = h;
          if (J.Cl) J.Cl[off] = f2bf(v - bf2f(h));
          if (J.Cf) J.Cf[off] = v;
        }
      }
      __syncthreads();
    }
    gridbar(p.bar, p.nblocks);
  }
}

// ---------------- fused init: split A, split B(hi), pack U, u_t weights -----
__global__ __launch_bounds__(256) void init_all(
    const float* __restrict__ A, const float* __restrict__ B,
    const float* __restrict__ uh,
    ushortT* N1h, ushortT* N1l, ushortT* T1h, ushortT* T1l,
    ushortT* WTh, ushortT* UTh, ushortT* UTl,
    const float* __restrict__ ynh, const float* __restrict__ sigma,
    const float* __restrict__ phi, const float* __restrict__ lambda_e,
    const float* __restrict__ phi_tilde, float* __restrict__ wvec,
    float* __restrict__ out, unsigned* __restrict__ bar) {
  __shared__ float w4[48];
  if (blockIdx.x == 0 && threadIdx.x < 8) bar[threadIdx.x] = 0u;
  if (blockIdx.x >= 5632) {
    // ---- u_t weight vectors ----
    int v = blockIdx.x - 5632;
    int p = threadIdx.x;
    float val = 0.f;
    if (v == 0) {
      val = ynh[(size_t)(L_HIST - 1) * 256 + p];
      out[512 + p] = 0.f;
    } else if (v <= 16) {
      int i = v - 1;
      float s = 0.f;
      for (int j = 0; j < 24; ++j)
        s += phi_tilde[j * 16 + i] * ynh[(size_t)(L_HIST - 2 - j) * 256 + p];
      val = powf(lambda_e[i], 0.25f) * s;
    } else if (v <= 33) {
      int l = v - 17;
      float s = 0.f;
      for (int k = 0; k < 25; ++k)
        s += phi[k * 17 + l] * ynh[(size_t)(L_HIST - 1 - k) * 256 + p];
      val = powf(sigma[l], 0.25f) * s;
    } else {
      int t = v - 34;
      int i = t / 17, l = t % 17;
      if (p < 48) {
        int m = p;
        int jlo = m - 24; if (jlo < 0) jlo = 0;
        int jhi = m; if (jhi > 23) jhi = 23;
        float s = 0.f;
        for (int j = jlo; j <= jhi; ++j)
          s += phi_tilde[j * 16 + i] * phi[(m - j) * 17 + l];
        w4[p] = s;
      }
      __syncthreads();
      float s = 0.f;
      for (int m = 0; m < 48; ++m)
        s += w4[m] * ynh[(size_t)(L_HIST - 3 - m) * 256 + p];
      val = powf(lambda_e[i], 0.25f) * powf(sigma[l], 0.25f) * s;
    }
    wvec[v * 256 + p] = val;
    return;
  }
  int idx = blockIdx.x * 256 + threadIdx.x;
  if (idx < 262144) {
    int r = idx >> 9, c = idx & 511;
    float x = A[idx];
    ushortT h = f2bf(x); ushortT l = f2bf(x - bf2f(h));
    N1h[idx] = h; N1l[idx] = l;
    T1h[c * 512 + r] = h; T1l[c * 512 + r] = l;
  } else if (idx < 262144 + 131072) {
    int i2 = idx - 262144;
    int d = i2 >> 8, c = i2 & 255;
    WTh[c * 512 + d] = f2bf(B[i2]);
  } else {
    int i2 = idx - 393216;          // < 128*8192
    int j = i2 >> 13, k = i2 & 8191;
    int tau = k >> 8, c = k & 255;
    float v = 0.f;
    if (j < 64) v = uh[(size_t)(L_HIST - 1 - (32 * j + tau)) * 256 + c];
    else if (j == 64 && tau < 16) v = uh[(size_t)(L_HIST - 1 - tau) * 256 + c];
    ushortT h = f2bf(v);
    UTh[i2] = h; UTl[i2] = f2bf(v - bf2f(h));
  }
}

// ---------------- host orchestration ----------------------------------------
extern "C" void kernel_launch(void* const* d_in, const int* in_sizes, int n_in,
                              void* d_out, int out_size, void* d_ws, size_t ws_size,
                              hipStream_t stream) {
  (void)in_sizes; (void)n_in; (void)out_size; (void)ws_size;
  const float* A   = (const float*)d_in[0];
  const float* B   = (const float*)d_in[1];
  const float* C   = (const float*)d_in[2];
  const float* M   = (const float*)d_in[3];
  const float* Mb  = (const float*)d_in[4];
  const float* sig = (const float*)d_in[5];
  const float* phi = (const float*)d_in[6];
  const float* lam = (const float*)d_in[7];
  const float* pt  = (const float*)d_in[8];
  const float* yh  = (const float*)d_in[9];
  const float* uh  = (const float*)d_in[10];
  const float* ynh = (const float*)d_in[11];
  float* out = (float*)d_out;
  char* base = (char*)d_ws;

  const size_t HMB = 512u * 1024u;
  const size_t SL = 512 * 512;            // elems per 512x512 plane
  ushortT* POW  = (ushortT*)base;                  // 16 slots x (hi+lo) = 16MB
  ushortT* WTh  = (ushortT*)(base + 32 * HMB);     // 8192x512  (8MB)
  ushortT* P1th = (ushortT*)(base + 48 * HMB);     // 7 x SL    (3.5MB)
  ushortT* P1tl = (ushortT*)(base + 55 * HMB);
  ushortT* P2th = (ushortT*)(base + 62 * HMB);
  ushortT* P2tl = (ushortT*)(base + 69 * HMB);
  float*   Pf1  = (float*)(base + 76 * HMB);       // 7 x SL fp32 (7MB)
  float*   Pf2  = (float*)(base + 90 * HMB);
  ushortT* UTh  = (ushortT*)(base + 104 * HMB);    // 128x8192 (2MB)
  ushortT* UTl  = (ushortT*)(base + 108 * HMB);
  float*   Qpart= (float*)(base + 112 * HMB);      // 16x512x128 fp32 (4MB)
  float*   Rpart= (float*)(base + 120 * HMB);      // 28x4096
  float*   Spart= Rpart + 28 * 4096;               // 28x512
  float*   wvec = Spart + 28 * 512;                // 306x256
  unsigned* bar = (unsigned*)(base + 126 * HMB);   // grid barrier state

  auto ph = [&](int i) { return POW + (size_t)i * 2 * SL; };
  auto pl = [&](int i) { return POW + (size_t)i * 2 * SL + SL; };
  // slots: 0:N1 1:T1 2:N2 3:T2 4:N4 5:T4 6:N8 7:T8 8:N16 9:T16
  //        10:N32 11:N64 12:N128 13:N256 14:N512 15:N1024
  auto e1h = [&](int j) { return P1th + (size_t)(j - 1) * SL; };
  auto e1l = [&](int j) { return P1tl + (size_t)(j - 1) * SL; };
  auto e2h = [&](int j) { return P2th + (size_t)(j - 1) * SL; };
  auto e2l = [&](int j) { return P2tl + (size_t)(j - 1) * SL; };

  Prm P;
  P.Wt = WTh; P.Uh = UTh; P.Ul = UTl;
  P.Qp = Qpart; P.Rp = Rpart; P.Sp = Spart;
  P.Pf1 = Pf1; P.Pf2 = Pf2;
  P.Mt = M; P.Mbar = Mb; P.wv = wvec; P.Cmat = C; P.yh = yh;
  P.outp = out; P.bar = bar;
  P.nblocks = 256;

  int jn = 0, si = 0, uv = 0;
  auto J_ = [&](const ushortT* Ph, const ushortT* Qh, const ushortT* Ql,
                ushortT* Ch, ushortT* Cl, float* Cf, int Mrows) {
    P.jobs[jn].Ph = Ph; P.jobs[jn].Qh = Qh; P.jobs[jn].Ql = Ql;
    P.jobs[jn].Ch = Ch; P.jobs[jn].Cl = Cl; P.jobs[jn].Cf = Cf;
    P.jobs[jn].M = Mrows; P.jobs[jn].tbase = 0; ++jn;
  };
  auto S_ = [&](int nj, int q, int r, int sg, int fin, int ut) {
    Step& s = P.st[si++];
    s.jbase = jn - nj; s.nj = nj;
    int tb = 0;
    for (int t = 0; t < nj; ++t) {
      P.jobs[s.jbase + t].tbase = tb;
      tb += (P.jobs[s.jbase + t].M >> 6) * 8;
    }
    s.qbase = tb; s.rbase = s.qbase + q; s.sbase = s.rbase + r;
    s.fbase = s.sbase + sg; s.utbase = s.fbase + fin; s.W = s.utbase + ut;
    s.ut0 = uv; uv += ut;
  };

  // step 1..11: dual power/W/stack chain (+qgemm @6, +rgemm @9, ut spread)
  J_(ph(0), ph(1), pl(1), ph(2), pl(2), nullptr, 512);              // N2
  J_(ph(1), ph(0), pl(0), ph(3), pl(3), nullptr, 512);              // T2
  J_(WTh, ph(0), pl(0), WTh + 256 * 512, nullptr, nullptr, 256);    // W1
  S_(3, 0, 0, 0, 0, 93);
  J_(ph(2), ph(3), pl(3), ph(4), pl(4), nullptr, 512);              // N4
  J_(ph(3), ph(2), pl(2), ph(5), pl(5), nullptr, 512);              // T4
  J_(WTh, ph(2), pl(2), WTh + 512 * 512, nullptr, nullptr, 512);    // W2:4
  S_(3, 0, 0, 0, 0, 93);
  J_(ph(4), ph(5), pl(5), ph(6), pl(6), nullptr, 512);              // N8
  J_(ph(5), ph(4), pl(4), ph(7), pl(7), nullptr, 512);              // T8
  J_(WTh, ph(4), pl(4), WTh + 1024 * 512, nullptr, nullptr, 1024);  // W4:8
  S_(3, 0, 0, 0, 0, 93);
  J_(ph(6), ph(7), pl(7), ph(8), pl(8), nullptr, 512);              // N16
  J_(ph(7), ph(6), pl(6), ph(9), pl(9), nullptr, 512);              // T16
  J_(WTh, ph(6), pl(6), WTh + 2048 * 512, nullptr, nullptr, 2048);  // W8:16
  S_(3, 0, 0, 0, 0, 93);
  J_(ph(8), ph(9), pl(9), ph(10), pl(10), nullptr, 512);            // N32
  J_(ph(9), ph(8), pl(8), e1h(1), e1l(1), Pf1, 512);                // T32
  J_(WTh, ph(8), pl(8), WTh + 4096 * 512, nullptr, nullptr, 4096);  // W16:32
  S_(3, 0, 0, 0, 0, 93);
  J_(ph(10), e1h(1), e1l(1), ph(11), pl(11), nullptr, 512);         // N64
  J_(e1h(1), ph(10), pl(10), e1h(2), e1l(2), Pf1 + SL, 512);        // T64
  S_(2, 256, 0, 0, 0, 93);                                          // + qgemm
  J_(ph(11), e1h(2), e1l(2), ph(12), pl(12), nullptr, 512);         // N128
  J_(e1h(1), ph(11), pl(11), e1h(3), e1l(3), Pf1 + 2 * SL, 1024);   // T96,T128
  S_(2, 0, 0, 0, 0, 93);
  J_(ph(12), e1h(4), e1l(4), ph(13), pl(13), nullptr, 512);         // N256
  J_(e1h(1), ph(12), pl(12), e1h(5), nullptr, Pf1 + 4 * SL, 1536);  // T160..224
  J_(e1h(4), ph(12), pl(12), e2h(1), e2l(1), Pf2, 512);             // T256
  S_(3, 0, 0, 0, 0, 93);
  J_(ph(13), e2h(1), e2l(1), ph(14), pl(14), nullptr, 512);         // N512
  J_(e2h(1), ph(13), pl(13), e2h(2), e2l(2), Pf2 + SL, 512);        // T512
  S_(2, 0, 56, 0, 0, 93);                                           // + rgemm
  J_(ph(14), e2h(2), e2l(2), ph(15), pl(15), nullptr, 512);         // N1024
  J_(e2h(1), ph(14), pl(14), e2h(3), nullptr, Pf2 + 2 * SL, 1024);  // T768,T1024
  S_(2, 0, 0, 0, 0, 93);
  J_(e2h(1), ph(15), pl(15), e2h(5), nullptr, Pf2 + 4 * SL, 1536);  // T1280..1792
  S_(1, 0, 0, 0, 0, 94);
  // step 12: S partials; step 13: finalize
  S_(0, 0, 0, 56, 0, 0);
  S_(0, 0, 0, 0, 64, 0);
  P.nsteps = si;

  init_all<<<5938, 256, 0, stream>>>(A, B, uh, ph(0), pl(0), ph(1), pl(1),
                                     WTh, UTh, UTl,
                                     ynh, sig, phi, lam, pt, wvec, out, bar);
  megachain<<<256, 256, 0, stream>>>(P);
}

// Round 6
// 564.917 us; speedup vs baseline: 2.8450x; 2.8450x over previous
//
#include <hip/hip_runtime.h>

#define L_HIST 2048
typedef unsigned short ushortT;
typedef __attribute__((ext_vector_type(8))) short bf16x8;
typedef __attribute__((ext_vector_type(4))) short bf16x4;
typedef __attribute__((ext_vector_type(16))) float f32x16;

__device__ __forceinline__ ushortT f2bf(float x) {
  union { float f; unsigned u; } v; v.f = x;
  unsigned r = (v.u + 0x7FFFu + ((v.u >> 16) & 1u)) >> 16;
  return (ushortT)r;
}
__device__ __forceinline__ float bf2f(ushortT h) {
  union { unsigned u; float f; } v; v.u = ((unsigned)h) << 16; return v.f;
}
__device__ __forceinline__ bf16x4 lo4(bf16x8 v) {
  return __builtin_shufflevector(v, v, 0, 1, 2, 3);
}
__device__ __forceinline__ bf16x4 hi4(bf16x8 v) {
  return __builtin_shufflevector(v, v, 4, 5, 6, 7);
}
__device__ __forceinline__ bf16x8 rd8(const ushortT* p) {
  bf16x4 a = *(const bf16x4*)p, b = *(const bf16x4*)(p + 4);
  return __builtin_shufflevector(a, b, 0, 1, 2, 3, 4, 5, 6, 7);
}

// ---------------- job-table mega kernel -------------------------------------
// Block ranges: [0,qbase) bf16 bt-GEMM jobs; [qbase,rbase) qgemm (W*U) blocks;
// [rbase,utbase) rgemm blocks; [utbase,grid) ut_gemv slices.
// LDS pad 34 (not 36): 3*4*64*34*2 = 52224 B -> 3 blocks/CU (was 2).
// Stride 34 ushorts = 17 dwords/row; 17 coprime 32 -> ds_read_b128 conflict-free.
struct Job {
  const ushortT *Ph, *Qh, *Ql;
  ushortT *Ch, *Cl;
  float *Cf;
  int M, tbase;
};
struct Prm {
  Job j[3]; int nj;
  int qbase, rbase, utbase, uv0;
  const ushortT *Wt, *Uh, *Ul;
  float *Qp;
  const float *Pf1; float *Rp;
  const float *Mt, *Mbar, *wv; float *outp;
};

__global__ __launch_bounds__(256) void mega(Prm p) {
  __shared__ __align__(16) ushortT As[4][64][34];
  __shared__ ushortT Bhs[4][64][34];
  __shared__ ushortT Bls[4][64][34];
  int bx = blockIdx.x;
  int tid = threadIdx.x;

  if (bx >= p.utbase) {
    // ---- u_t gemv slice (hidden under latency-bound chain) ----
    int u = bx - p.utbase + p.uv0;
    int n = u & 255, h = u >> 8;
    int lane = tid & 63, wid = tid >> 6;
    int vs = (306 * h) >> 2, ve = (306 * (h + 1)) >> 2;
    float4 acc = {0.f, 0.f, 0.f, 0.f};
#pragma unroll 4
    for (int v = vs + wid; v < ve; v += 4) {
      const float* mat = (v < 17 ? p.Mbar : p.Mt - 17 * 65536) + (size_t)v * 65536;
      float4 mv = ((const float4*)(mat + (size_t)n * 256))[lane];
      float4 wv = ((const float4*)(p.wv + (size_t)v * 256))[lane];
      acc.x += mv.x * wv.x; acc.y += mv.y * wv.y;
      acc.z += mv.z * wv.z; acc.w += mv.w * wv.w;
    }
    float a = (acc.x + acc.y) + (acc.z + acc.w);
    for (int off = 32; off > 0; off >>= 1) a += __shfl_down(a, off);
    if (lane == 0) atomicAdd(&p.outp[512 + n], a);
    return;
  }

  if (bx >= p.rbase) {
    // ---- R partials, 256-thread variant (2 blocks per (j1,dc)) ----
    int r = bx - p.rbase;
    float* Qs = (float*)&As[0][0][0];   // reuse LDS as [128][8] fp32 (16KB<=17408B)
    int pr = r >> 1, mh = r & 1;
    int j1 = (pr >> 2) + 1, dc = pr & 3;
    int d0 = dc * 128, m = mh * 256 + tid;
    for (int i = tid; i < 1024; i += 256) {
      int dd = i >> 3, jj = i & 7;
      float s = 0.f;
#pragma unroll
      for (int z = 0; z < 16; ++z)
        s += p.Qp[((size_t)z * 512 + d0 + dd) * 128 + j1 + 8 * jj];
      Qs[dd * 8 + jj] = s;
    }
    __syncthreads();
    float acc[8];
#pragma unroll
    for (int jj = 0; jj < 8; ++jj) acc[jj] = 0.f;
    for (int d = 0; d < 128; ++d) {
      float tv = p.Pf1[((size_t)(j1 - 1) * 512 + d0 + d) * 512 + m];
      float4 q0 = *(const float4*)&Qs[d * 8];
      float4 q1 = *(const float4*)&Qs[d * 8 + 4];
      acc[0] += tv * q0.x; acc[1] += tv * q0.y; acc[2] += tv * q0.z; acc[3] += tv * q0.w;
      acc[4] += tv * q1.x; acc[5] += tv * q1.y; acc[6] += tv * q1.z; acc[7] += tv * q1.w;
    }
    float* dst = p.Rp + (size_t)((j1 - 1) * 4 + dc) * 4096 + m * 8;
#pragma unroll
    for (int jj = 0; jj < 8; ++jj) dst[jj] = acc[jj];
    return;
  }

  if (bx >= p.qbase) {
    // ---- Q = W*U, z-split 16 (512-K slices), K-chunked 128 ----
    int q = bx - p.qbase;
    int z = q & 15, mtile = (q >> 4) & 7, ntile = q >> 7;
    int m0 = mtile * 64, n0 = ntile * 64, k0 = z * 512;
    int lane = tid & 63, wave = tid >> 6;
    int wm = (wave & 1) * 32, wn = (wave >> 1) * 32;
    int fr = lane & 31, fk = (lane >> 5) * 8;
    int ka = tid & 31, ma = (tid >> 5) * 8;
    int jb = tid >> 2, kb = (tid & 3) * 8;

    const ushortT* pW  = p.Wt + (size_t)(k0 + ka) * 512 + m0 + ma;
    const ushortT* pUh = p.Uh + (size_t)(n0 + jb) * 8192 + k0 + kb;
    const ushortT* pUl = p.Ul + (size_t)(n0 + jb) * 8192 + k0 + kb;

    bf16x8 rW[4], rUh[4], rUl[4];
#pragma unroll
    for (int s = 0; s < 4; ++s) {
      rW[s]  = *(const bf16x8*)(pW + (size_t)(s * 32) * 512);
      rUh[s] = *(const bf16x8*)(pUh + s * 32);
      rUl[s] = *(const bf16x8*)(pUl + s * 32);
    }
    f32x16 acc;
#pragma unroll
    for (int i = 0; i < 16; ++i) acc[i] = 0.f;

    for (int c = 0; c < 4; ++c) {
#pragma unroll
      for (int s = 0; s < 4; ++s) {
#pragma unroll
        for (int e = 0; e < 8; ++e) As[s][ma + e][ka] = (ushortT)rW[s][e];
        *(bf16x4*)&Bhs[s][jb][kb]     = lo4(rUh[s]);
        *(bf16x4*)&Bhs[s][jb][kb + 4] = hi4(rUh[s]);
        *(bf16x4*)&Bls[s][jb][kb]     = lo4(rUl[s]);
        *(bf16x4*)&Bls[s][jb][kb + 4] = hi4(rUl[s]);
      }
      __syncthreads();
      if (c < 3) {
        int off = (c + 1) * 128;
#pragma unroll
        for (int s = 0; s < 4; ++s) {
          rW[s]  = *(const bf16x8*)(pW + (size_t)(off + s * 32) * 512);
          rUh[s] = *(const bf16x8*)(pUh + off + s * 32);
          rUl[s] = *(const bf16x8*)(pUl + off + s * 32);
        }
      }
#pragma unroll
      for (int s = 0; s < 4; ++s)
#pragma unroll
        for (int ks = 0; ks < 32; ks += 16) {
          bf16x8 a  = rd8(&As[s][wm + fr][ks + fk]);
          bf16x8 bh = rd8(&Bhs[s][wn + fr][ks + fk]);
          bf16x8 bl = rd8(&Bls[s][wn + fr][ks + fk]);
          acc = __builtin_amdgcn_mfma_f32_32x32x16_bf16(a, bh, acc, 0, 0, 0);
          acc = __builtin_amdgcn_mfma_f32_32x32x16_bf16(a, bl, acc, 0, 0, 0);
        }
      __syncthreads();
    }
#pragma unroll
    for (int i = 0; i < 16; ++i) {
      int rr = wm + (i & 3) + ((i >> 2) << 3) + ((lane >> 5) << 2);
      int cc = wn + (lane & 31);
      p.Qp[((size_t)z * 512 + m0 + rr) * 128 + n0 + cc] = acc[i];
    }
    return;
  }

  // ---- dual-product bf16 bt-GEMM jobs: D[m][n]=sum_k Ph[m][k]*(Qh+Ql)[n][k]
  int ji = 0;
  if (p.nj > 1 && bx >= p.j[1].tbase) ji = 1;
  if (p.nj > 2 && bx >= p.j[2].tbase) ji = 2;
  Job J = p.j[ji];
  int lt = bx - J.tbase;
  int mt = J.M >> 6;
  int mtile = lt % mt, ntile = lt / mt;
  size_t m0 = (size_t)mtile * 64, n0 = (size_t)ntile * 64;

  int lane = tid & 63, wave = tid >> 6;
  int wm = (wave & 1) * 32, wn = (wave >> 1) * 32;
  int fr = lane & 31, fk = (lane >> 5) * 8;
  int row = tid >> 2, kp = (tid & 3) * 8;

  const ushortT* pA  = J.Ph + (m0 + row) * 512 + kp;
  const ushortT* pBh = J.Qh + (n0 + row) * 512 + kp;
  const ushortT* pBl = J.Ql + (n0 + row) * 512 + kp;

  bf16x8 rA[4], rBh[4], rBl[4];
#pragma unroll
  for (int s = 0; s < 4; ++s) {
    rA[s]  = *(const bf16x8*)(pA  + s * 32);
    rBh[s] = *(const bf16x8*)(pBh + s * 32);
    rBl[s] = *(const bf16x8*)(pBl + s * 32);
  }

  f32x16 acc;
#pragma unroll
  for (int i = 0; i < 16; ++i) acc[i] = 0.f;

  for (int c = 0; c < 4; ++c) {
#pragma unroll
    for (int s = 0; s < 4; ++s) {
      *(bf16x4*)&As[s][row][kp]      = lo4(rA[s]);
      *(bf16x4*)&As[s][row][kp + 4]  = hi4(rA[s]);
      *(bf16x4*)&Bhs[s][row][kp]     = lo4(rBh[s]);
      *(bf16x4*)&Bhs[s][row][kp + 4] = hi4(rBh[s]);
      *(bf16x4*)&Bls[s][row][kp]     = lo4(rBl[s]);
      *(bf16x4*)&Bls[s][row][kp + 4] = hi4(rBl[s]);
    }
    __syncthreads();
    if (c < 3) {
      int off = (c + 1) * 128;
#pragma unroll
      for (int s = 0; s < 4; ++s) {
        rA[s]  = *(const bf16x8*)(pA  + off + s * 32);
        rBh[s] = *(const bf16x8*)(pBh + off + s * 32);
        rBl[s] = *(const bf16x8*)(pBl + off + s * 32);
      }
    }
#pragma unroll
    for (int s = 0; s < 4; ++s)
#pragma unroll
      for (int ks = 0; ks < 32; ks += 16) {
        bf16x8 a  = rd8(&As[s][wm + fr][ks + fk]);
        bf16x8 bh = rd8(&Bhs[s][wn + fr][ks + fk]);
        bf16x8 bl = rd8(&Bls[s][wn + fr][ks + fk]);
        acc = __builtin_amdgcn_mfma_f32_32x32x16_bf16(a, bh, acc, 0, 0, 0);
        acc = __builtin_amdgcn_mfma_f32_32x32x16_bf16(a, bl, acc, 0, 0, 0);
      }
    __syncthreads();
  }
#pragma unroll
  for (int i = 0; i < 16; ++i) {
    int r = wm + (i & 3) + ((i >> 2) << 3) + ((lane >> 5) << 2);
    int c = wn + (lane & 31);
    float v = acc[i];
    size_t off = (m0 + r) * 512 + (n0 + c);
    ushortT h = f2bf(v);
    J.Ch[off] = h;
    if (J.Cl) J.Cl[off] = f2bf(v - bf2f(h));
    if (J.Cf) J.Cf[off] = v;
  }
}

// ---------------- fused init: split A, split B(hi), pack U, u_t weights -----
__global__ __launch_bounds__(256) void init_all(
    const float* __restrict__ A, const float* __restrict__ B,
    const float* __restrict__ uh,
    ushortT* N1h, ushortT* N1l, ushortT* T1h, ushortT* T1l,
    ushortT* WTh, ushortT* UTh, ushortT* UTl,
    const float* __restrict__ ynh, const float* __restrict__ sigma,
    const float* __restrict__ phi, const float* __restrict__ lambda_e,
    const float* __restrict__ phi_tilde, float* __restrict__ wvec,
    float* __restrict__ out) {
  __shared__ float w4[48];
  if (blockIdx.x >= 5632) {
    // ---- u_t weight vectors (former weights_kernel, verified R1-R5) ----
    int v = blockIdx.x - 5632;
    int p = threadIdx.x;
    float val = 0.f;
    if (v == 0) {
      val = ynh[(size_t)(L_HIST - 1) * 256 + p];
      out[512 + p] = 0.f;
    } else if (v <= 16) {
      int i = v - 1;
      float s = 0.f;
      for (int j = 0; j < 24; ++j)
        s += phi_tilde[j * 16 + i] * ynh[(size_t)(L_HIST - 2 - j) * 256 + p];
      val = powf(lambda_e[i], 0.25f) * s;
    } else if (v <= 33) {
      int l = v - 17;
      float s = 0.f;
      for (int k = 0; k < 25; ++k)
        s += phi[k * 17 + l] * ynh[(size_t)(L_HIST - 1 - k) * 256 + p];
      val = powf(sigma[l], 0.25f) * s;
    } else {
      int t = v - 34;
      int i = t / 17, l = t % 17;
      if (p < 48) {
        int m = p;
        int jlo = m - 24; if (jlo < 0) jlo = 0;
        int jhi = m; if (jhi > 23) jhi = 23;
        float s = 0.f;
        for (int j = jlo; j <= jhi; ++j)
          s += phi_tilde[j * 16 + i] * phi[(m - j) * 17 + l];
        w4[p] = s;
      }
      __syncthreads();
      float s = 0.f;
      for (int m = 0; m < 48; ++m)
        s += w4[m] * ynh[(size_t)(L_HIST - 3 - m) * 256 + p];
      val = powf(lambda_e[i], 0.25f) * powf(sigma[l], 0.25f) * s;
    }
    wvec[v * 256 + p] = val;
    return;
  }
  int idx = blockIdx.x * 256 + threadIdx.x;
  if (idx < 262144) {
    int r = idx >> 9, c = idx & 511;
    float x = A[idx];
    ushortT h = f2bf(x); ushortT l = f2bf(x - bf2f(h));
    N1h[idx] = h; N1l[idx] = l;
    T1h[c * 512 + r] = h; T1l[c * 512 + r] = l;
  } else if (idx < 262144 + 131072) {
    int i2 = idx - 262144;
    int d = i2 >> 8, c = i2 & 255;
    WTh[c * 512 + d] = f2bf(B[i2]);
  } else {
    int i2 = idx - 393216;          // < 128*8192
    int j = i2 >> 13, k = i2 & 8191;
    int tau = k >> 8, c = k & 255;
    float v = 0.f;
    if (j < 64) v = uh[(size_t)(L_HIST - 1 - (32 * j + tau)) * 256 + c];
    else if (j == 64 && tau < 16) v = uh[(size_t)(L_HIST - 1 - tau) * 256 + c];
    ushortT h = f2bf(v);
    UTh[i2] = h; UTl[i2] = f2bf(v - bf2f(h));
  }
}

// ---------------- S partials (assembles Rb rows inline), z=16 ---------------
__global__ __launch_bounds__(512) void sgemm(const float* __restrict__ Pf2,
                                             const float* __restrict__ Qpart,
                                             const float* __restrict__ Rpart,
                                             float* __restrict__ Spart) {
  int j2 = blockIdx.x + 1;     // 1..7
  int dc = blockIdx.y;         // 0..3
  int d0 = dc * 128;
  int m = threadIdx.x;
  __shared__ float Rs[128];
  if (threadIdx.x < 128) {
    int dd = threadIdx.x;
    float s = 0.f;
#pragma unroll
    for (int z = 0; z < 16; ++z)
      s += Qpart[((size_t)z * 512 + d0 + dd) * 128 + 8 * j2];
    for (int p = 0; p < 28; ++p)
      s += Rpart[(size_t)p * 4096 + (d0 + dd) * 8 + j2];
    Rs[dd] = s;
  }
  __syncthreads();
  float acc = 0.f;
  for (int d = 0; d < 128; ++d)
    acc += Pf2[((size_t)(j2 - 1) * 512 + d0 + d) * 512 + m] * Rs[d];
  Spart[(size_t)((j2 - 1) * 4 + dc) * 512 + m] = acc;
}

// ---------------- finalize: y_nat & pred (assembles s inline), z=16 ---------
__global__ __launch_bounds__(64) void finalize_kernel(
    const float* __restrict__ Cmat, const float* __restrict__ Qpart,
    const float* __restrict__ Rpart, const float* __restrict__ Spart,
    const float* __restrict__ yh, float* __restrict__ out) {
  int p = blockIdx.x;
  int lane = threadIdx.x;
  float a1 = 0.f, a2 = 0.f;
  for (int t = lane; t < 512; t += 64) {
    float sb = 0.f, qp = 0.f;
#pragma unroll
    for (int z = 0; z < 16; ++z) {
      sb += Qpart[((size_t)z * 512 + t) * 128 + 0];
      qp += Qpart[((size_t)z * 512 + t) * 128 + 64];
    }
    for (int q = 0; q < 28; ++q) {
      sb += Rpart[(size_t)q * 4096 + t * 8];
      sb += Spart[(size_t)q * 512 + t];
    }
    float cv = Cmat[(size_t)p * 512 + t];
    a1 += cv * sb;
    a2 += cv * qp;
  }
  for (int off = 32; off > 0; off >>= 1) {
    a1 += __shfl_down(a1, off);
    a2 += __shfl_down(a2, off);
  }
  if (lane == 0) {
    float ynat = yh[(size_t)(L_HIST - 1) * 256 + p] - a1;
    out[p] = ynat;
    out[256 + p] = ynat + a2;
  }
}

// ---------------- host orchestration ----------------------------------------
extern "C" void kernel_launch(void* const* d_in, const int* in_sizes, int n_in,
                              void* d_out, int out_size, void* d_ws, size_t ws_size,
                              hipStream_t stream) {
  (void)in_sizes; (void)n_in; (void)out_size; (void)ws_size;
  const float* A   = (const float*)d_in[0];
  const float* B   = (const float*)d_in[1];
  const float* C   = (const float*)d_in[2];
  const float* M   = (const float*)d_in[3];
  const float* Mb  = (const float*)d_in[4];
  const float* sig = (const float*)d_in[5];
  const float* phi = (const float*)d_in[6];
  const float* lam = (const float*)d_in[7];
  const float* pt  = (const float*)d_in[8];
  const float* yh  = (const float*)d_in[9];
  const float* uh  = (const float*)d_in[10];
  const float* ynh = (const float*)d_in[11];
  float* out = (float*)d_out;
  char* base = (char*)d_ws;

  // compact layout, 0.5MB granularity; proven round-2 footprint
  const size_t HMB = 512u * 1024u;
  const size_t SL = 512 * 512;            // elems per 512x512 plane
  ushortT* POW  = (ushortT*)base;                  // 16 slots x (hi+lo) = 16MB
  ushortT* WTh  = (ushortT*)(base + 32 * HMB);     // 8192x512  (8MB)
  ushortT* P1th = (ushortT*)(base + 48 * HMB);     // 7 x SL    (3.5MB)
  ushortT* P1tl = (ushortT*)(base + 55 * HMB);
  ushortT* P2th = (ushortT*)(base + 62 * HMB);
  ushortT* P2tl = (ushortT*)(base + 69 * HMB);
  float*   Pf1  = (float*)(base + 76 * HMB);       // 7 x SL fp32 (7MB)
  float*   Pf2  = (float*)(base + 90 * HMB);
  ushortT* UTh  = (ushortT*)(base + 104 * HMB);    // 128x8192 (2MB)
  ushortT* UTl  = (ushortT*)(base + 108 * HMB);
  float*   Qpart= (float*)(base + 112 * HMB);      // 16x512x128 fp32 (4MB)
  float*   Rpart= (float*)(base + 120 * HMB);      // 28x4096
  float*   Spart= Rpart + 28 * 4096;               // 28x512
  float*   wvec = Spart + 28 * 512;                // 306x256

  auto ph = [&](int i) { return POW + (size_t)i * 2 * SL; };
  auto pl = [&](int i) { return POW + (size_t)i * 2 * SL + SL; };
  // slots: 0:N1 1:T1 2:N2 3:T2 4:N4 5:T4 6:N8 7:T8 8:N16 9:T16
  //        10:N32 11:N64 12:N128 13:N256 14:N512 15:N1024
  auto e1h = [&](int j) { return P1th + (size_t)(j - 1) * SL; };
  auto e1l = [&](int j) { return P1tl + (size_t)(j - 1) * SL; };
  auto e2h = [&](int j) { return P2th + (size_t)(j - 1) * SL; };
  auto e2l = [&](int j) { return P2tl + (size_t)(j - 1) * SL; };

  auto mkJ = [&](const ushortT* Ph, const ushortT* Qh, const ushortT* Ql,
                 ushortT* Ch, ushortT* Cl, float* Cf, int Mrows) {
    Job j; j.Ph = Ph; j.Qh = Qh; j.Ql = Ql;
    j.Ch = Ch; j.Cl = Cl; j.Cf = Cf; j.M = Mrows; j.tbase = 0; return j;
  };
  int uvoff = 0;
  auto runL = [&](Job j0, Job j1, Job j2, int nj, int qcnt, int rcnt, int utcnt) {
    Prm p; p.j[0] = j0; p.j[1] = (nj > 1) ? j1 : j0; p.j[2] = (nj > 2) ? j2 : j0;
    p.nj = nj;
    int tb = 0;
    for (int i = 0; i < nj; ++i) { p.j[i].tbase = tb; tb += (p.j[i].M >> 6) * 8; }
    p.qbase = tb; p.rbase = tb + qcnt; p.utbase = p.rbase + rcnt;
    p.uv0 = uvoff; uvoff += utcnt;
    p.Wt = WTh; p.Uh = UTh; p.Ul = UTl; p.Qp = Qpart;
    p.Pf1 = Pf1; p.Rp = Rpart;
    p.Mt = M; p.Mbar = Mb; p.wv = wvec; p.outp = out;
    mega<<<p.utbase + utcnt, 256, 0, stream>>>(p);
  };

  // ---- init + u_t weights (one node; weights feed the ut slices below) ----
  init_all<<<5938, 256, 0, stream>>>(A, B, uh, ph(0), pl(0), ph(1), pl(1),
                                     WTh, UTh, UTl,
                                     ynh, sig, phi, lam, pt, wvec, out);

  Job d = mkJ(ph(0), ph(1), pl(1), ph(2), pl(2), nullptr, 512); // dummy
  // ---- dual power/W/stack chain: 11 launches, ut slices spread across all,
  //      qgemm blocks ride L6 (WTh done after L5), rgemm rides L9 (Pf1 done L8)
  runL(mkJ(ph(0), ph(1), pl(1), ph(2), pl(2), nullptr, 512),              // N2
       mkJ(ph(1), ph(0), pl(0), ph(3), pl(3), nullptr, 512),              // T2
       mkJ(WTh, ph(0), pl(0), WTh + 256 * 512, nullptr, nullptr, 256),    // W1
       3, 0, 0, 93);
  runL(mkJ(ph(2), ph(3), pl(3), ph(4), pl(4), nullptr, 512),              // N4
       mkJ(ph(3), ph(2), pl(2), ph(5), pl(5), nullptr, 512),              // T4
       mkJ(WTh, ph(2), pl(2), WTh + 512 * 512, nullptr, nullptr, 512),    // W2:4
       3, 0, 0, 93);
  runL(mkJ(ph(4), ph(5), pl(5), ph(6), pl(6), nullptr, 512),              // N8
       mkJ(ph(5), ph(4), pl(4), ph(7), pl(7), nullptr, 512),              // T8
       mkJ(WTh, ph(4), pl(4), WTh + 1024 * 512, nullptr, nullptr, 1024),  // W4:8
       3, 0, 0, 93);
  runL(mkJ(ph(6), ph(7), pl(7), ph(8), pl(8), nullptr, 512),              // N16
       mkJ(ph(7), ph(6), pl(6), ph(9), pl(9), nullptr, 512),              // T16
       mkJ(WTh, ph(6), pl(6), WTh + 2048 * 512, nullptr, nullptr, 2048),  // W8:16
       3, 0, 0, 93);
  runL(mkJ(ph(8), ph(9), pl(9), ph(10), pl(10), nullptr, 512),            // N32
       mkJ(ph(9), ph(8), pl(8), e1h(1), e1l(1), Pf1, 512),                // T32
       mkJ(WTh, ph(8), pl(8), WTh + 4096 * 512, nullptr, nullptr, 4096),  // W16:32
       3, 0, 0, 93);
  runL(mkJ(ph(10), e1h(1), e1l(1), ph(11), pl(11), nullptr, 512),         // N64
       mkJ(e1h(1), ph(10), pl(10), e1h(2), e1l(2), Pf1 + SL, 512),        // T64
       d, 2, 256, 0, 93);                                                 // + qgemm
  runL(mkJ(ph(11), e1h(2), e1l(2), ph(12), pl(12), nullptr, 512),         // N128
       mkJ(e1h(1), ph(11), pl(11), e1h(3), e1l(3), Pf1 + 2 * SL, 1024),   // T96,T128
       d, 2, 0, 0, 93);
  runL(mkJ(ph(12), e1h(4), e1l(4), ph(13), pl(13), nullptr, 512),         // N256
       mkJ(e1h(1), ph(12), pl(12), e1h(5), nullptr, Pf1 + 4 * SL, 1536),  // T160..224
       mkJ(e1h(4), ph(12), pl(12), e2h(1), e2l(1), Pf2, 512), 3, 0, 0, 93); // T256
  runL(mkJ(ph(13), e2h(1), e2l(1), ph(14), pl(14), nullptr, 512),         // N512
       mkJ(e2h(1), ph(13), pl(13), e2h(2), e2l(2), Pf2 + SL, 512),        // T512
       d, 2, 0, 56, 93);                                                  // + rgemm
  runL(mkJ(ph(14), e2h(2), e2l(2), ph(15), pl(15), nullptr, 512),         // N1024
       mkJ(e2h(1), ph(14), pl(14), e2h(3), nullptr, Pf2 + 2 * SL, 1024),  // T768,T1024
       d, 2, 0, 0, 93);
  runL(mkJ(e2h(1), ph(15), pl(15), e2h(5), nullptr, Pf2 + 4 * SL, 1536),  // T1280..1792
       d, d, 1, 0, 0, 94);

  // ---- tail: S partials need Pf2 planes from L11; finalize needs Spart ----
  sgemm<<<dim3(7, 4), 512, 0, stream>>>(Pf2, Qpart, Rpart, Spart);
  finalize_kernel<<<256, 64, 0, stream>>>(C, Qpart, Rpart, Spart, yh, out);
}

// Round 7
// 292.904 us; speedup vs baseline: 5.4871x; 1.9287x over previous
//
#include <hip/hip_runtime.h>

#define L_HIST 2048
typedef unsigned short ushortT;
typedef __attribute__((ext_vector_type(8))) short bf16x8;
typedef __attribute__((ext_vector_type(4))) short bf16x4;
typedef __attribute__((ext_vector_type(16))) float f32x16;

__device__ __forceinline__ ushortT f2bf(float x) {
  union { float f; unsigned u; } v; v.f = x;
  unsigned r = (v.u + 0x7FFFu + ((v.u >> 16) & 1u)) >> 16;
  return (ushortT)r;
}
__device__ __forceinline__ float bf2f(ushortT h) {
  union { unsigned u; float f; } v; v.u = ((unsigned)h) << 16; return v.f;
}
__device__ __forceinline__ bf16x4 lo4(bf16x8 v) {
  return __builtin_shufflevector(v, v, 0, 1, 2, 3);
}
__device__ __forceinline__ bf16x4 hi4(bf16x8 v) {
  return __builtin_shufflevector(v, v, 4, 5, 6, 7);
}
__device__ __forceinline__ bf16x8 rd8(const ushortT* p) {
  bf16x4 a = *(const bf16x4*)p, b = *(const bf16x4*)(p + 4);
  return __builtin_shufflevector(a, b, 0, 1, 2, 3, 4, 5, 6, 7);
}

// ---------------- job-table mega kernel -------------------------------------
// Block ranges: [0,qbase) bf16 bt-GEMM jobs; [qbase,rbase) qgemm (W*U) blocks;
// [rbase,utbase) rgemm blocks; [utbase,grid) ut_gemv slices.
// LDS pad 36 (proven; pad 34 regressed 299->565 us via b128 misalign/conflicts).
// 2-deep register prefetch: chunk c+2 loads issued during chunk c's MFMA.
struct Job {
  const ushortT *Ph, *Qh, *Ql;
  ushortT *Ch, *Cl;
  float *Cf;
  int M, tbase;
};
struct Prm {
  Job j[3]; int nj;
  int qbase, rbase, utbase, uv0;
  const ushortT *Wt, *Uh, *Ul;
  float *Qp;
  const float *Pf1; float *Rp;
  const float *Mt, *Mbar, *wv; float *outp;
};

__global__ __launch_bounds__(256) void mega(Prm p) {
  __shared__ __align__(16) ushortT As[4][64][36];
  __shared__ ushortT Bhs[4][64][36];
  __shared__ ushortT Bls[4][64][36];
  int bx = blockIdx.x;
  int tid = threadIdx.x;

  if (bx >= p.utbase) {
    // ---- u_t gemv slice (hidden under latency-bound chain) ----
    int u = bx - p.utbase + p.uv0;
    int n = u & 255, h = u >> 8;
    int lane = tid & 63, wid = tid >> 6;
    int vs = (306 * h) >> 2, ve = (306 * (h + 1)) >> 2;
    float4 acc = {0.f, 0.f, 0.f, 0.f};
#pragma unroll 4
    for (int v = vs + wid; v < ve; v += 4) {
      const float* mat = (v < 17 ? p.Mbar : p.Mt - 17 * 65536) + (size_t)v * 65536;
      float4 mv = ((const float4*)(mat + (size_t)n * 256))[lane];
      float4 wv = ((const float4*)(p.wv + (size_t)v * 256))[lane];
      acc.x += mv.x * wv.x; acc.y += mv.y * wv.y;
      acc.z += mv.z * wv.z; acc.w += mv.w * wv.w;
    }
    float a = (acc.x + acc.y) + (acc.z + acc.w);
    for (int off = 32; off > 0; off >>= 1) a += __shfl_down(a, off);
    if (lane == 0) atomicAdd(&p.outp[512 + n], a);
    return;
  }

  if (bx >= p.rbase) {
    // ---- R partials, 256-thread variant (2 blocks per (j1,dc)) ----
    int r = bx - p.rbase;
    float* Qs = (float*)&As[0][0][0];   // reuse LDS as [128][8] fp32
    int pr = r >> 1, mh = r & 1;
    int j1 = (pr >> 2) + 1, dc = pr & 3;
    int d0 = dc * 128, m = mh * 256 + tid;
    for (int i = tid; i < 1024; i += 256) {
      int dd = i >> 3, jj = i & 7;
      float s = 0.f;
#pragma unroll
      for (int z = 0; z < 16; ++z)
        s += p.Qp[((size_t)z * 512 + d0 + dd) * 128 + j1 + 8 * jj];
      Qs[dd * 8 + jj] = s;
    }
    __syncthreads();
    float acc[8];
#pragma unroll
    for (int jj = 0; jj < 8; ++jj) acc[jj] = 0.f;
    for (int d = 0; d < 128; ++d) {
      float tv = p.Pf1[((size_t)(j1 - 1) * 512 + d0 + d) * 512 + m];
      float4 q0 = *(const float4*)&Qs[d * 8];
      float4 q1 = *(const float4*)&Qs[d * 8 + 4];
      acc[0] += tv * q0.x; acc[1] += tv * q0.y; acc[2] += tv * q0.z; acc[3] += tv * q0.w;
      acc[4] += tv * q1.x; acc[5] += tv * q1.y; acc[6] += tv * q1.z; acc[7] += tv * q1.w;
    }
    float* dst = p.Rp + (size_t)((j1 - 1) * 4 + dc) * 4096 + m * 8;
#pragma unroll
    for (int jj = 0; jj < 8; ++jj) dst[jj] = acc[jj];
    return;
  }

  if (bx >= p.qbase) {
    // ---- Q = W*U, z-split 16 (512-K slices), K-chunked 128, 2-deep prefetch
    int q = bx - p.qbase;
    int z = q & 15, mtile = (q >> 4) & 7, ntile = q >> 7;
    int m0 = mtile * 64, n0 = ntile * 64, k0 = z * 512;
    int lane = tid & 63, wave = tid >> 6;
    int wm = (wave & 1) * 32, wn = (wave >> 1) * 32;
    int fr = lane & 31, fk = (lane >> 5) * 8;
    int ka = tid & 31, ma = (tid >> 5) * 8;
    int jb = tid >> 2, kb = (tid & 3) * 8;

    const ushortT* pW  = p.Wt + (size_t)(k0 + ka) * 512 + m0 + ma;
    const ushortT* pUh = p.Uh + (size_t)(n0 + jb) * 8192 + k0 + kb;
    const ushortT* pUl = p.Ul + (size_t)(n0 + jb) * 8192 + k0 + kb;

    bf16x8 rW[2][4], rUh[2][4], rUl[2][4];
#pragma unroll
    for (int s = 0; s < 4; ++s) {
      rW[0][s]  = *(const bf16x8*)(pW + (size_t)(s * 32) * 512);
      rUh[0][s] = *(const bf16x8*)(pUh + s * 32);
      rUl[0][s] = *(const bf16x8*)(pUl + s * 32);
      rW[1][s]  = *(const bf16x8*)(pW + (size_t)(128 + s * 32) * 512);
      rUh[1][s] = *(const bf16x8*)(pUh + 128 + s * 32);
      rUl[1][s] = *(const bf16x8*)(pUl + 128 + s * 32);
    }
    f32x16 acc;
#pragma unroll
    for (int i = 0; i < 16; ++i) acc[i] = 0.f;

#pragma unroll
    for (int c = 0; c < 4; ++c) {
      const int cs = c & 1;
#pragma unroll
      for (int s = 0; s < 4; ++s) {
#pragma unroll
        for (int e = 0; e < 8; ++e) As[s][ma + e][ka] = (ushortT)rW[cs][s][e];
        *(bf16x4*)&Bhs[s][jb][kb]     = lo4(rUh[cs][s]);
        *(bf16x4*)&Bhs[s][jb][kb + 4] = hi4(rUh[cs][s]);
        *(bf16x4*)&Bls[s][jb][kb]     = lo4(rUl[cs][s]);
        *(bf16x4*)&Bls[s][jb][kb + 4] = hi4(rUl[cs][s]);
      }
      __syncthreads();
      if (c < 2) {
        int off = (c + 2) * 128;
#pragma unroll
        for (int s = 0; s < 4; ++s) {
          rW[cs][s]  = *(const bf16x8*)(pW + (size_t)(off + s * 32) * 512);
          rUh[cs][s] = *(const bf16x8*)(pUh + off + s * 32);
          rUl[cs][s] = *(const bf16x8*)(pUl + off + s * 32);
        }
      }
#pragma unroll
      for (int s = 0; s < 4; ++s)
#pragma unroll
        for (int ks = 0; ks < 32; ks += 16) {
          bf16x8 a  = rd8(&As[s][wm + fr][ks + fk]);
          bf16x8 bh = rd8(&Bhs[s][wn + fr][ks + fk]);
          bf16x8 bl = rd8(&Bls[s][wn + fr][ks + fk]);
          acc = __builtin_amdgcn_mfma_f32_32x32x16_bf16(a, bh, acc, 0, 0, 0);
          acc = __builtin_amdgcn_mfma_f32_32x32x16_bf16(a, bl, acc, 0, 0, 0);
        }
      __syncthreads();
    }
#pragma unroll
    for (int i = 0; i < 16; ++i) {
      int rr = wm + (i & 3) + ((i >> 2) << 3) + ((lane >> 5) << 2);
      int cc = wn + (lane & 31);
      p.Qp[((size_t)z * 512 + m0 + rr) * 128 + n0 + cc] = acc[i];
    }
    return;
  }

  // ---- dual-product bf16 bt-GEMM jobs: D[m][n]=sum_k Ph[m][k]*(Qh+Ql)[n][k]
  int ji = 0;
  if (p.nj > 1 && bx >= p.j[1].tbase) ji = 1;
  if (p.nj > 2 && bx >= p.j[2].tbase) ji = 2;
  Job J = p.j[ji];
  int lt = bx - J.tbase;
  int mt = J.M >> 6;
  int mtile = lt % mt, ntile = lt / mt;
  size_t m0 = (size_t)mtile * 64, n0 = (size_t)ntile * 64;

  int lane = tid & 63, wave = tid >> 6;
  int wm = (wave & 1) * 32, wn = (wave >> 1) * 32;
  int fr = lane & 31, fk = (lane >> 5) * 8;
  int row = tid >> 2, kp = (tid & 3) * 8;

  const ushortT* pA  = J.Ph + (m0 + row) * 512 + kp;
  const ushortT* pBh = J.Qh + (n0 + row) * 512 + kp;
  const ushortT* pBl = J.Ql + (n0 + row) * 512 + kp;

  bf16x8 rA[2][4], rBh[2][4], rBl[2][4];
#pragma unroll
  for (int s = 0; s < 4; ++s) {
    rA[0][s]  = *(const bf16x8*)(pA  + s * 32);
    rBh[0][s] = *(const bf16x8*)(pBh + s * 32);
    rBl[0][s] = *(const bf16x8*)(pBl + s * 32);
    rA[1][s]  = *(const bf16x8*)(pA  + 128 + s * 32);
    rBh[1][s] = *(const bf16x8*)(pBh + 128 + s * 32);
    rBl[1][s] = *(const bf16x8*)(pBl + 128 + s * 32);
  }

  f32x16 acc;
#pragma unroll
  for (int i = 0; i < 16; ++i) acc[i] = 0.f;

#pragma unroll
  for (int c = 0; c < 4; ++c) {
    const int cs = c & 1;
#pragma unroll
    for (int s = 0; s < 4; ++s) {
      *(bf16x4*)&As[s][row][kp]      = lo4(rA[cs][s]);
      *(bf16x4*)&As[s][row][kp + 4]  = hi4(rA[cs][s]);
      *(bf16x4*)&Bhs[s][row][kp]     = lo4(rBh[cs][s]);
      *(bf16x4*)&Bhs[s][row][kp + 4] = hi4(rBh[cs][s]);
      *(bf16x4*)&Bls[s][row][kp]     = lo4(rBl[cs][s]);
      *(bf16x4*)&Bls[s][row][kp + 4] = hi4(rBl[cs][s]);
    }
    __syncthreads();
    if (c < 2) {
      int off = (c + 2) * 128;
#pragma unroll
      for (int s = 0; s < 4; ++s) {
        rA[cs][s]  = *(const bf16x8*)(pA  + off + s * 32);
        rBh[cs][s] = *(const bf16x8*)(pBh + off + s * 32);
        rBl[cs][s] = *(const bf16x8*)(pBl + off + s * 32);
      }
    }
#pragma unroll
    for (int s = 0; s < 4; ++s)
#pragma unroll
      for (int ks = 0; ks < 32; ks += 16) {
        bf16x8 a  = rd8(&As[s][wm + fr][ks + fk]);
        bf16x8 bh = rd8(&Bhs[s][wn + fr][ks + fk]);
        bf16x8 bl = rd8(&Bls[s][wn + fr][ks + fk]);
        acc = __builtin_amdgcn_mfma_f32_32x32x16_bf16(a, bh, acc, 0, 0, 0);
        acc = __builtin_amdgcn_mfma_f32_32x32x16_bf16(a, bl, acc, 0, 0, 0);
      }
    __syncthreads();
  }
#pragma unroll
  for (int i = 0; i < 16; ++i) {
    int r = wm + (i & 3) + ((i >> 2) << 3) + ((lane >> 5) << 2);
    int c = wn + (lane & 31);
    float v = acc[i];
    size_t off = (m0 + r) * 512 + (n0 + c);
    ushortT h = f2bf(v);
    J.Ch[off] = h;
    if (J.Cl) J.Cl[off] = f2bf(v - bf2f(h));
    if (J.Cf) J.Cf[off] = v;
  }
}

// ---------------- fused init: split A, split B(hi), pack U, u_t weights -----
__global__ __launch_bounds__(256) void init_all(
    const float* __restrict__ A, const float* __restrict__ B,
    const float* __restrict__ uh,
    ushortT* N1h, ushortT* N1l, ushortT* T1h, ushortT* T1l,
    ushortT* WTh, ushortT* UTh, ushortT* UTl,
    const float* __restrict__ ynh, const float* __restrict__ sigma,
    const float* __restrict__ phi, const float* __restrict__ lambda_e,
    const float* __restrict__ phi_tilde, float* __restrict__ wvec,
    float* __restrict__ out) {
  __shared__ float w4[48];
  if (blockIdx.x >= 5632) {
    // ---- u_t weight vectors (former weights_kernel, verified R1-R5) ----
    int v = blockIdx.x - 5632;
    int p = threadIdx.x;
    float val = 0.f;
    if (v == 0) {
      val = ynh[(size_t)(L_HIST - 1) * 256 + p];
      out[512 + p] = 0.f;
    } else if (v <= 16) {
      int i = v - 1;
      float s = 0.f;
      for (int j = 0; j < 24; ++j)
        s += phi_tilde[j * 16 + i] * ynh[(size_t)(L_HIST - 2 - j) * 256 + p];
      val = powf(lambda_e[i], 0.25f) * s;
    } else if (v <= 33) {
      int l = v - 17;
      float s = 0.f;
      for (int k = 0; k < 25; ++k)
        s += phi[k * 17 + l] * ynh[(size_t)(L_HIST - 1 - k) * 256 + p];
      val = powf(sigma[l], 0.25f) * s;
    } else {
      int t = v - 34;
      int i = t / 17, l = t % 17;
      if (p < 48) {
        int m = p;
        int jlo = m - 24; if (jlo < 0) jlo = 0;
        int jhi = m; if (jhi > 23) jhi = 23;
        float s = 0.f;
        for (int j = jlo; j <= jhi; ++j)
          s += phi_tilde[j * 16 + i] * phi[(m - j) * 17 + l];
        w4[p] = s;
      }
      __syncthreads();
      float s = 0.f;
      for (int m = 0; m < 48; ++m)
        s += w4[m] * ynh[(size_t)(L_HIST - 3 - m) * 256 + p];
      val = powf(lambda_e[i], 0.25f) * powf(sigma[l], 0.25f) * s;
    }
    wvec[v * 256 + p] = val;
    return;
  }
  int idx = blockIdx.x * 256 + threadIdx.x;
  if (idx < 262144) {
    int r = idx >> 9, c = idx & 511;
    float x = A[idx];
    ushortT h = f2bf(x); ushortT l = f2bf(x - bf2f(h));
    N1h[idx] = h; N1l[idx] = l;
    T1h[c * 512 + r] = h; T1l[c * 512 + r] = l;
  } else if (idx < 262144 + 131072) {
    int i2 = idx - 262144;
    int d = i2 >> 8, c = i2 & 255;
    WTh[c * 512 + d] = f2bf(B[i2]);
  } else {
    int i2 = idx - 393216;          // < 128*8192
    int j = i2 >> 13, k = i2 & 8191;
    int tau = k >> 8, c = k & 255;
    float v = 0.f;
    if (j < 64) v = uh[(size_t)(L_HIST - 1 - (32 * j + tau)) * 256 + c];
    else if (j == 64 && tau < 16) v = uh[(size_t)(L_HIST - 1 - tau) * 256 + c];
    ushortT h = f2bf(v);
    UTh[i2] = h; UTl[i2] = f2bf(v - bf2f(h));
  }
}

// ---------------- S partials (assembles Rb rows inline), z=16 ---------------
__global__ __launch_bounds__(512) void sgemm(const float* __restrict__ Pf2,
                                             const float* __restrict__ Qpart,
                                             const float* __restrict__ Rpart,
                                             float* __restrict__ Spart) {
  int j2 = blockIdx.x + 1;     // 1..7
  int dc = blockIdx.y;         // 0..3
  int d0 = dc * 128;
  int m = threadIdx.x;
  __shared__ float Rs[128];
  if (threadIdx.x < 128) {
    int dd = threadIdx.x;
    float s = 0.f;
#pragma unroll
    for (int z = 0; z < 16; ++z)
      s += Qpart[((size_t)z * 512 + d0 + dd) * 128 + 8 * j2];
    for (int p = 0; p < 28; ++p)
      s += Rpart[(size_t)p * 4096 + (d0 + dd) * 8 + j2];
    Rs[dd] = s;
  }
  __syncthreads();
  float acc = 0.f;
  for (int d = 0; d < 128; ++d)
    acc += Pf2[((size_t)(j2 - 1) * 512 + d0 + d) * 512 + m] * Rs[d];
  Spart[(size_t)((j2 - 1) * 4 + dc) * 512 + m] = acc;
}

// ---------------- finalize: y_nat & pred (assembles s inline), z=16 ---------
__global__ __launch_bounds__(64) void finalize_kernel(
    const float* __restrict__ Cmat, const float* __restrict__ Qpart,
    const float* __restrict__ Rpart, const float* __restrict__ Spart,
    const float* __restrict__ yh, float* __restrict__ out) {
  int p = blockIdx.x;
  int lane = threadIdx.x;
  float a1 = 0.f, a2 = 0.f;
  for (int t = lane; t < 512; t += 64) {
    float sb = 0.f, qp = 0.f;
#pragma unroll
    for (int z = 0; z < 16; ++z) {
      sb += Qpart[((size_t)z * 512 + t) * 128 + 0];
      qp += Qpart[((size_t)z * 512 + t) * 128 + 64];
    }
    for (int q = 0; q < 28; ++q) {
      sb += Rpart[(size_t)q * 4096 + t * 8];
      sb += Spart[(size_t)q * 512 + t];
    }
    float cv = Cmat[(size_t)p * 512 + t];
    a1 += cv * sb;
    a2 += cv * qp;
  }
  for (int off = 32; off > 0; off >>= 1) {
    a1 += __shfl_down(a1, off);
    a2 += __shfl_down(a2, off);
  }
  if (lane == 0) {
    float ynat = yh[(size_t)(L_HIST - 1) * 256 + p] - a1;
    out[p] = ynat;
    out[256 + p] = ynat + a2;
  }
}

// ---------------- host orchestration ----------------------------------------
extern "C" void kernel_launch(void* const* d_in, const int* in_sizes, int n_in,
                              void* d_out, int out_size, void* d_ws, size_t ws_size,
                              hipStream_t stream) {
  (void)in_sizes; (void)n_in; (void)out_size; (void)ws_size;
  const float* A   = (const float*)d_in[0];
  const float* B   = (const float*)d_in[1];
  const float* C   = (const float*)d_in[2];
  const float* M   = (const float*)d_in[3];
  const float* Mb  = (const float*)d_in[4];
  const float* sig = (const float*)d_in[5];
  const float* phi = (const float*)d_in[6];
  const float* lam = (const float*)d_in[7];
  const float* pt  = (const float*)d_in[8];
  const float* yh  = (const float*)d_in[9];
  const float* uh  = (const float*)d_in[10];
  const float* ynh = (const float*)d_in[11];
  float* out = (float*)d_out;
  char* base = (char*)d_ws;

  // compact layout, 0.5MB granularity; proven round-2 footprint
  const size_t HMB = 512u * 1024u;
  const size_t SL = 512 * 512;            // elems per 512x512 plane
  ushortT* POW  = (ushortT*)base;                  // 16 slots x (hi+lo) = 16MB
  ushortT* WTh  = (ushortT*)(base + 32 * HMB);     // 8192x512  (8MB)
  ushortT* P1th = (ushortT*)(base + 48 * HMB);     // 7 x SL    (3.5MB)
  ushortT* P1tl = (ushortT*)(base + 55 * HMB);
  ushortT* P2th = (ushortT*)(base + 62 * HMB);
  ushortT* P2tl = (ushortT*)(base + 69 * HMB);
  float*   Pf1  = (float*)(base + 76 * HMB);       // 7 x SL fp32 (7MB)
  float*   Pf2  = (float*)(base + 90 * HMB);
  ushortT* UTh  = (ushortT*)(base + 104 * HMB);    // 128x8192 (2MB)
  ushortT* UTl  = (ushortT*)(base + 108 * HMB);
  float*   Qpart= (float*)(base + 112 * HMB);      // 16x512x128 fp32 (4MB)
  float*   Rpart= (float*)(base + 120 * HMB);      // 28x4096
  float*   Spart= Rpart + 28 * 4096;               // 28x512
  float*   wvec = Spart + 28 * 512;                // 306x256

  auto ph = [&](int i) { return POW + (size_t)i * 2 * SL; };
  auto pl = [&](int i) { return POW + (size_t)i * 2 * SL + SL; };
  // slots: 0:N1 1:T1 2:N2 3:T2 4:N4 5:T4 6:N8 7:T8 8:N16 9:T16
  //        10:N32 11:N64 12:N128 13:N256 14:N512 15:N1024
  auto e1h = [&](int j) { return P1th + (size_t)(j - 1) * SL; };
  auto e1l = [&](int j) { return P1tl + (size_t)(j - 1) * SL; };
  auto e2h = [&](int j) { return P2th + (size_t)(j - 1) * SL; };
  auto e2l = [&](int j) { return P2tl + (size_t)(j - 1) * SL; };

  auto mkJ = [&](const ushortT* Ph, const ushortT* Qh, const ushortT* Ql,
                 ushortT* Ch, ushortT* Cl, float* Cf, int Mrows) {
    Job j; j.Ph = Ph; j.Qh = Qh; j.Ql = Ql;
    j.Ch = Ch; j.Cl = Cl; j.Cf = Cf; j.M = Mrows; j.tbase = 0; return j;
  };
  int uvoff = 0;
  auto runL = [&](Job j0, Job j1, Job j2, int nj, int qcnt, int rcnt, int utcnt) {
    Prm p; p.j[0] = j0; p.j[1] = (nj > 1) ? j1 : j0; p.j[2] = (nj > 2) ? j2 : j0;
    p.nj = nj;
    int tb = 0;
    for (int i = 0; i < nj; ++i) { p.j[i].tbase = tb; tb += (p.j[i].M >> 6) * 8; }
    p.qbase = tb; p.rbase = tb + qcnt; p.utbase = p.rbase + rcnt;
    p.uv0 = uvoff; uvoff += utcnt;
    p.Wt = WTh; p.Uh = UTh; p.Ul = UTl; p.Qp = Qpart;
    p.Pf1 = Pf1; p.Rp = Rpart;
    p.Mt = M; p.Mbar = Mb; p.wv = wvec; p.outp = out;
    mega<<<p.utbase + utcnt, 256, 0, stream>>>(p);
  };

  // ---- init + u_t weights (one node; weights feed the ut slices below) ----
  init_all<<<5938, 256, 0, stream>>>(A, B, uh, ph(0), pl(0), ph(1), pl(1),
                                     WTh, UTh, UTl,
                                     ynh, sig, phi, lam, pt, wvec, out);

  Job d = mkJ(ph(0), ph(1), pl(1), ph(2), pl(2), nullptr, 512); // dummy
  // ---- dual power/W/stack chain: 11 launches, ut slices spread across all,
  //      qgemm blocks ride L6 (WTh done after L5), rgemm rides L9 (Pf1 done L8)
  runL(mkJ(ph(0), ph(1), pl(1), ph(2), pl(2), nullptr, 512),              // N2
       mkJ(ph(1), ph(0), pl(0), ph(3), pl(3), nullptr, 512),              // T2
       mkJ(WTh, ph(0), pl(0), WTh + 256 * 512, nullptr, nullptr, 256),    // W1
       3, 0, 0, 93);
  runL(mkJ(ph(2), ph(3), pl(3), ph(4), pl(4), nullptr, 512),              // N4
       mkJ(ph(3), ph(2), pl(2), ph(5), pl(5), nullptr, 512),              // T4
       mkJ(WTh, ph(2), pl(2), WTh + 512 * 512, nullptr, nullptr, 512),    // W2:4
       3, 0, 0, 93);
  runL(mkJ(ph(4), ph(5), pl(5), ph(6), pl(6), nullptr, 512),              // N8
       mkJ(ph(5), ph(4), pl(4), ph(7), pl(7), nullptr, 512),              // T8
       mkJ(WTh, ph(4), pl(4), WTh + 1024 * 512, nullptr, nullptr, 1024),  // W4:8
       3, 0, 0, 93);
  runL(mkJ(ph(6), ph(7), pl(7), ph(8), pl(8), nullptr, 512),              // N16
       mkJ(ph(7), ph(6), pl(6), ph(9), pl(9), nullptr, 512),              // T16
       mkJ(WTh, ph(6), pl(6), WTh + 2048 * 512, nullptr, nullptr, 2048),  // W8:16
       3, 0, 0, 93);
  runL(mkJ(ph(8), ph(9), pl(9), ph(10), pl(10), nullptr, 512),            // N32
       mkJ(ph(9), ph(8), pl(8), e1h(1), e1l(1), Pf1, 512),                // T32
       mkJ(WTh, ph(8), pl(8), WTh + 4096 * 512, nullptr, nullptr, 4096),  // W16:32
       3, 0, 0, 93);
  runL(mkJ(ph(10), e1h(1), e1l(1), ph(11), pl(11), nullptr, 512),         // N64
       mkJ(e1h(1), ph(10), pl(10), e1h(2), e1l(2), Pf1 + SL, 512),        // T64
       d, 2, 256, 0, 93);                                                 // + qgemm
  runL(mkJ(ph(11), e1h(2), e1l(2), ph(12), pl(12), nullptr, 512),         // N128
       mkJ(e1h(1), ph(11), pl(11), e1h(3), e1l(3), Pf1 + 2 * SL, 1024),   // T96,T128
       d, 2, 0, 0, 93);
  runL(mkJ(ph(12), e1h(4), e1l(4), ph(13), pl(13), nullptr, 512),         // N256
       mkJ(e1h(1), ph(12), pl(12), e1h(5), nullptr, Pf1 + 4 * SL, 1536),  // T160..224
       mkJ(e1h(4), ph(12), pl(12), e2h(1), e2l(1), Pf2, 512), 3, 0, 0, 93); // T256
  runL(mkJ(ph(13), e2h(1), e2l(1), ph(14), pl(14), nullptr, 512),         // N512
       mkJ(e2h(1), ph(13), pl(13), e2h(2), e2l(2), Pf2 + SL, 512),        // T512
       d, 2, 0, 56, 93);                                                  // + rgemm
  runL(mkJ(ph(14), e2h(2), e2l(2), ph(15), pl(15), nullptr, 512),         // N1024
       mkJ(e2h(1), ph(14), pl(14), e2h(3), nullptr, Pf2 + 2 * SL, 1024),  // T768,T1024
       d, 2, 0, 0, 93);
  runL(mkJ(e2h(1), ph(15), pl(15), e2h(5), nullptr, Pf2 + 4 * SL, 1536),  // T1280..1792
       d, d, 1, 0, 0, 94);

  // ---- tail: S partials need Pf2 planes from L11; finalize needs Spart ----
  sgemm<<<dim3(7, 4), 512, 0, stream>>>(Pf2, Qpart, Rpart, Spart);
  finalize_kernel<<<256, 64, 0, stream>>>(C, Qpart, Rpart, Spart, yh, out);
}

// Round 8
// 290.788 us; speedup vs baseline: 5.5270x; 1.0073x over previous
//
#include <hip/hip_runtime.h>

#define L_HIST 2048
typedef unsigned short ushortT;
typedef __attribute__((ext_vector_type(8))) short bf16x8;
typedef __attribute__((ext_vector_type(4))) short bf16x4;
typedef __attribute__((ext_vector_type(16))) float f32x16;

__device__ __forceinline__ ushortT f2bf(float x) {
  union { float f; unsigned u; } v; v.f = x;
  unsigned r = (v.u + 0x7FFFu + ((v.u >> 16) & 1u)) >> 16;
  return (ushortT)r;
}
__device__ __forceinline__ float bf2f(ushortT h) {
  union { unsigned u; float f; } v; v.u = ((unsigned)h) << 16; return v.f;
}
__device__ __forceinline__ bf16x4 lo4(bf16x8 v) {
  return __builtin_shufflevector(v, v, 0, 1, 2, 3);
}
__device__ __forceinline__ bf16x4 hi4(bf16x8 v) {
  return __builtin_shufflevector(v, v, 4, 5, 6, 7);
}
__device__ __forceinline__ bf16x8 rd8(const ushortT* p) {
  bf16x4 a = *(const bf16x4*)p, b = *(const bf16x4*)(p + 4);
  return __builtin_shufflevector(a, b, 0, 1, 2, 3, 4, 5, 6, 7);
}

#define SLc 262144  // 512*512

// ---------------- job-table mega kernel -------------------------------------
// Ranges: [0,qbase) GEMM jobs | [qbase,rabase) qgemm | [rabase,rbbase) rgemmA
// | [rbbase,utbase) rgemmB | [utbase,..) ut slices.
// Power-composition: R_{j1>=5} = A^128 * (A^{32(j1-4)} q)  (planes T32..T128),
// so high Pf1/Pf2 planes + N1024 + L11 are never materialized.
struct Job {
  const ushortT *Ph, *Qh, *Ql;
  ushortT *Ch, *Cl;
  float *Cf;
  int M, tbase;
};
struct Prm {
  Job j[3]; int nj;
  int qbase, rabase, rbbase, utbase, uv0;
  const ushortT *Wt, *Uh, *Ul;
  float *Qp;
  const float *Pf1; float *Rp, *Vp;
  const float *Mt, *Mbar, *wv; float *outp;
};

__global__ __launch_bounds__(256) void mega(Prm p) {
  __shared__ __align__(16) ushortT As[4][64][36];
  __shared__ ushortT Bhs[4][64][36];
  __shared__ ushortT Bls[4][64][36];
  int bx = blockIdx.x;
  int tid = threadIdx.x;

  if (bx >= p.utbase) {
    // ---- u_t gemv slice (8-deep unroll for MLP) ----
    int u = bx - p.utbase + p.uv0;
    int n = u & 255, h = u >> 8;
    int lane = tid & 63, wid = tid >> 6;
    int vs = (306 * h) >> 2, ve = (306 * (h + 1)) >> 2;
    float4 acc = {0.f, 0.f, 0.f, 0.f};
#pragma unroll 8
    for (int v = vs + wid; v < ve; v += 4) {
      const float* mat = (v < 17 ? p.Mbar : p.Mt - 17 * 65536) + (size_t)v * 65536;
      float4 mv = ((const float4*)(mat + (size_t)n * 256))[lane];
      float4 wv = ((const float4*)(p.wv + (size_t)v * 256))[lane];
      acc.x += mv.x * wv.x; acc.y += mv.y * wv.y;
      acc.z += mv.z * wv.z; acc.w += mv.w * wv.w;
    }
    float a = (acc.x + acc.y) + (acc.z + acc.w);
    for (int off = 32; off > 0; off >>= 1) a += __shfl_down(a, off);
    if (lane == 0) atomicAdd(&p.outp[512 + n], a);
    return;
  }

  if (bx >= p.rbbase) {
    // ---- rgemm stage B: R_4 = T128^T q4 ; R_{5..7} = T128^T V_{j1} ----
    int r = bx - p.rbbase;              // 0..31
    int j1 = 4 + (r >> 3);
    int dc = (r >> 1) & 3, mh = r & 1;
    int d0 = dc * 128, m = mh * 256 + tid;
    float* Qs = (float*)&As[0][0][0];
    for (int i = tid; i < 1024; i += 256) {
      int dd = i >> 3, jj = i & 7;
      float s = 0.f;
      if (j1 == 4) {
#pragma unroll
        for (int z = 0; z < 16; ++z)
          s += p.Qp[((size_t)z * 512 + d0 + dd) * 128 + 4 + 8 * jj];
      } else {
#pragma unroll
        for (int q = 0; q < 4; ++q)
          s += p.Vp[(size_t)((j1 - 5) * 4 + q) * 4096 + (d0 + dd) * 8 + jj];
      }
      Qs[dd * 8 + jj] = s;
    }
    __syncthreads();
    float acc[8];
#pragma unroll
    for (int jj = 0; jj < 8; ++jj) acc[jj] = 0.f;
    for (int d = 0; d < 128; ++d) {
      float tv = p.Pf1[(size_t)3 * SLc + (size_t)(d0 + d) * 512 + m];
      float4 q0 = *(const float4*)&Qs[d * 8];
      float4 q1 = *(const float4*)&Qs[d * 8 + 4];
      acc[0] += tv * q0.x; acc[1] += tv * q0.y; acc[2] += tv * q0.z; acc[3] += tv * q0.w;
      acc[4] += tv * q1.x; acc[5] += tv * q1.y; acc[6] += tv * q1.z; acc[7] += tv * q1.w;
    }
    float* dst = p.Rp + (size_t)((j1 - 1) * 4 + dc) * 4096 + m * 8;
#pragma unroll
    for (int jj = 0; jj < 8; ++jj) dst[jj] = acc[jj];
    return;
  }

  if (bx >= p.rabase) {
    // ---- rgemm stage A: R_{1..3} (planes 0..2) + V_{5..7} (planes 0..2) ----
    int r = bx - p.rabase;              // 0..47
    int isV = (r >= 24);
    int rr = isV ? r - 24 : r;
    int j1 = (isV ? 5 : 1) + (rr >> 3);
    int dc = (rr >> 1) & 3, mh = rr & 1;
    int plane = isV ? (j1 - 5) : (j1 - 1);
    int d0 = dc * 128, m = mh * 256 + tid;
    float* Qs = (float*)&As[0][0][0];
    for (int i = tid; i < 1024; i += 256) {
      int dd = i >> 3, jj = i & 7;
      float s = 0.f;
#pragma unroll
      for (int z = 0; z < 16; ++z)
        s += p.Qp[((size_t)z * 512 + d0 + dd) * 128 + j1 + 8 * jj];
      Qs[dd * 8 + jj] = s;
    }
    __syncthreads();
    float acc[8];
#pragma unroll
    for (int jj = 0; jj < 8; ++jj) acc[jj] = 0.f;
    for (int d = 0; d < 128; ++d) {
      float tv = p.Pf1[(size_t)plane * SLc + (size_t)(d0 + d) * 512 + m];
      float4 q0 = *(const float4*)&Qs[d * 8];
      float4 q1 = *(const float4*)&Qs[d * 8 + 4];
      acc[0] += tv * q0.x; acc[1] += tv * q0.y; acc[2] += tv * q0.z; acc[3] += tv * q0.w;
      acc[4] += tv * q1.x; acc[5] += tv * q1.y; acc[6] += tv * q1.z; acc[7] += tv * q1.w;
    }
    float* dst = (isV ? p.Vp + (size_t)((j1 - 5) * 4 + dc) * 4096
                      : p.Rp + (size_t)((j1 - 1) * 4 + dc) * 4096) + m * 8;
#pragma unroll
    for (int jj = 0; jj < 8; ++jj) dst[jj] = acc[jj];
    return;
  }

  if (bx >= p.qbase) {
    // ---- Q = W*U, z-split 16 (512-K slices), K-chunked 128, 2-deep prefetch
    int q = bx - p.qbase;
    int z = q & 15, mtile = (q >> 4) & 7, ntile = q >> 7;
    int m0 = mtile * 64, n0 = ntile * 64, k0 = z * 512;
    int lane = tid & 63, wave = tid >> 6;
    int wm = (wave & 1) * 32, wn = (wave >> 1) * 32;
    int fr = lane & 31, fk = (lane >> 5) * 8;
    int ka = tid & 31, ma = (tid >> 5) * 8;
    int jb = tid >> 2, kb = (tid & 3) * 8;

    const ushortT* pW  = p.Wt + (size_t)(k0 + ka) * 512 + m0 + ma;
    const ushortT* pUh = p.Uh + (size_t)(n0 + jb) * 8192 + k0 + kb;
    const ushortT* pUl = p.Ul + (size_t)(n0 + jb) * 8192 + k0 + kb;

    bf16x8 rW[2][4], rUh[2][4], rUl[2][4];
#pragma unroll
    for (int s = 0; s < 4; ++s) {
      rW[0][s]  = *(const bf16x8*)(pW + (size_t)(s * 32) * 512);
      rUh[0][s] = *(const bf16x8*)(pUh + s * 32);
      rUl[0][s] = *(const bf16x8*)(pUl + s * 32);
      rW[1][s]  = *(const bf16x8*)(pW + (size_t)(128 + s * 32) * 512);
      rUh[1][s] = *(const bf16x8*)(pUh + 128 + s * 32);
      rUl[1][s] = *(const bf16x8*)(pUl + 128 + s * 32);
    }
    f32x16 acc;
#pragma unroll
    for (int i = 0; i < 16; ++i) acc[i] = 0.f;

#pragma unroll
    for (int c = 0; c < 4; ++c) {
      const int cs = c & 1;
#pragma unroll
      for (int s = 0; s < 4; ++s) {
#pragma unroll
        for (int e = 0; e < 8; ++e) As[s][ma + e][ka] = (ushortT)rW[cs][s][e];
        *(bf16x4*)&Bhs[s][jb][kb]     = lo4(rUh[cs][s]);
        *(bf16x4*)&Bhs[s][jb][kb + 4] = hi4(rUh[cs][s]);
        *(bf16x4*)&Bls[s][jb][kb]     = lo4(rUl[cs][s]);
        *(bf16x4*)&Bls[s][jb][kb + 4] = hi4(rUl[cs][s]);
      }
      __syncthreads();
      if (c < 2) {
        int off = (c + 2) * 128;
#pragma unroll
        for (int s = 0; s < 4; ++s) {
          rW[cs][s]  = *(const bf16x8*)(pW + (size_t)(off + s * 32) * 512);
          rUh[cs][s] = *(const bf16x8*)(pUh + off + s * 32);
          rUl[cs][s] = *(const bf16x8*)(pUl + off + s * 32);
        }
      }
#pragma unroll
      for (int s = 0; s < 4; ++s)
#pragma unroll
        for (int ks = 0; ks < 32; ks += 16) {
          bf16x8 a  = rd8(&As[s][wm + fr][ks + fk]);
          bf16x8 bh = rd8(&Bhs[s][wn + fr][ks + fk]);
          bf16x8 bl = rd8(&Bls[s][wn + fr][ks + fk]);
          acc = __builtin_amdgcn_mfma_f32_32x32x16_bf16(a, bh, acc, 0, 0, 0);
          acc = __builtin_amdgcn_mfma_f32_32x32x16_bf16(a, bl, acc, 0, 0, 0);
        }
      __syncthreads();
    }
#pragma unroll
    for (int i = 0; i < 16; ++i) {
      int rr = wm + (i & 3) + ((i >> 2) << 3) + ((lane >> 5) << 2);
      int cc = wn + (lane & 31);
      p.Qp[((size_t)z * 512 + m0 + rr) * 128 + n0 + cc] = acc[i];
    }
    return;
  }

  // ---- dual-product bf16 bt-GEMM jobs: D[m][n]=sum_k Ph[m][k]*(Qh+Ql)[n][k]
  int ji = 0;
  if (p.nj > 1 && bx >= p.j[1].tbase) ji = 1;
  if (p.nj > 2 && bx >= p.j[2].tbase) ji = 2;
  Job J = p.j[ji];
  int lt = bx - J.tbase;
  int mt = J.M >> 6;
  int mtile = lt % mt, ntile = lt / mt;
  size_t m0 = (size_t)mtile * 64, n0 = (size_t)ntile * 64;

  int lane = tid & 63, wave = tid >> 6;
  int wm = (wave & 1) * 32, wn = (wave >> 1) * 32;
  int fr = lane & 31, fk = (lane >> 5) * 8;
  int row = tid >> 2, kp = (tid & 3) * 8;

  const ushortT* pA  = J.Ph + (m0 + row) * 512 + kp;
  const ushortT* pBh = J.Qh + (n0 + row) * 512 + kp;
  const ushortT* pBl = J.Ql + (n0 + row) * 512 + kp;

  bf16x8 rA[2][4], rBh[2][4], rBl[2][4];
#pragma unroll
  for (int s = 0; s < 4; ++s) {
    rA[0][s]  = *(const bf16x8*)(pA  + s * 32);
    rBh[0][s] = *(const bf16x8*)(pBh + s * 32);
    rBl[0][s] = *(const bf16x8*)(pBl + s * 32);
    rA[1][s]  = *(const bf16x8*)(pA  + 128 + s * 32);
    rBh[1][s] = *(const bf16x8*)(pBh + 128 + s * 32);
    rBl[1][s] = *(const bf16x8*)(pBl + 128 + s * 32);
  }

  f32x16 acc;
#pragma unroll
  for (int i = 0; i < 16; ++i) acc[i] = 0.f;

#pragma unroll
  for (int c = 0; c < 4; ++c) {
    const int cs = c & 1;
#pragma unroll
    for (int s = 0; s < 4; ++s) {
      *(bf16x4*)&As[s][row][kp]      = lo4(rA[cs][s]);
      *(bf16x4*)&As[s][row][kp + 4]  = hi4(rA[cs][s]);
      *(bf16x4*)&Bhs[s][row][kp]     = lo4(rBh[cs][s]);
      *(bf16x4*)&Bhs[s][row][kp + 4] = hi4(rBh[cs][s]);
      *(bf16x4*)&Bls[s][row][kp]     = lo4(rBl[cs][s]);
      *(bf16x4*)&Bls[s][row][kp + 4] = hi4(rBl[cs][s]);
    }
    __syncthreads();
    if (c < 2) {
      int off = (c + 2) * 128;
#pragma unroll
      for (int s = 0; s < 4; ++s) {
        rA[cs][s]  = *(const bf16x8*)(pA  + off + s * 32);
        rBh[cs][s] = *(const bf16x8*)(pBh + off + s * 32);
        rBl[cs][s] = *(const bf16x8*)(pBl + off + s * 32);
      }
    }
#pragma unroll
    for (int s = 0; s < 4; ++s)
#pragma unroll
      for (int ks = 0; ks < 32; ks += 16) {
        bf16x8 a  = rd8(&As[s][wm + fr][ks + fk]);
        bf16x8 bh = rd8(&Bhs[s][wn + fr][ks + fk]);
        bf16x8 bl = rd8(&Bls[s][wn + fr][ks + fk]);
        acc = __builtin_amdgcn_mfma_f32_32x32x16_bf16(a, bh, acc, 0, 0, 0);
        acc = __builtin_amdgcn_mfma_f32_32x32x16_bf16(a, bl, acc, 0, 0, 0);
      }
    __syncthreads();
  }
#pragma unroll
  for (int i = 0; i < 16; ++i) {
    int r = wm + (i & 3) + ((i >> 2) << 3) + ((lane >> 5) << 2);
    int c = wn + (lane & 31);
    float v = acc[i];
    size_t off = (m0 + r) * 512 + (n0 + c);
    ushortT h = f2bf(v);
    J.Ch[off] = h;
    if (J.Cl) J.Cl[off] = f2bf(v - bf2f(h));
    if (J.Cf) J.Cf[off] = v;
  }
}

// ---------------- fused init: split A, split B(hi), pack U, u_t weights -----
__global__ __launch_bounds__(256) void init_all(
    const float* __restrict__ A, const float* __restrict__ B,
    const float* __restrict__ uh,
    ushortT* N1h, ushortT* N1l, ushortT* T1h, ushortT* T1l,
    ushortT* WTh, ushortT* UTh, ushortT* UTl,
    const float* __restrict__ ynh, const float* __restrict__ sigma,
    const float* __restrict__ phi, const float* __restrict__ lambda_e,
    const float* __restrict__ phi_tilde, float* __restrict__ wvec,
    float* __restrict__ out) {
  __shared__ float w4[48];
  if (blockIdx.x >= 5632) {
    int v = blockIdx.x - 5632;
    int p = threadIdx.x;
    float val = 0.f;
    if (v == 0) {
      val = ynh[(size_t)(L_HIST - 1) * 256 + p];
      out[512 + p] = 0.f;
    } else if (v <= 16) {
      int i = v - 1;
      float s = 0.f;
      for (int j = 0; j < 24; ++j)
        s += phi_tilde[j * 16 + i] * ynh[(size_t)(L_HIST - 2 - j) * 256 + p];
      val = powf(lambda_e[i], 0.25f) * s;
    } else if (v <= 33) {
      int l = v - 17;
      float s = 0.f;
      for (int k = 0; k < 25; ++k)
        s += phi[k * 17 + l] * ynh[(size_t)(L_HIST - 1 - k) * 256 + p];
      val = powf(sigma[l], 0.25f) * s;
    } else {
      int t = v - 34;
      int i = t / 17, l = t % 17;
      if (p < 48) {
        int m = p;
        int jlo = m - 24; if (jlo < 0) jlo = 0;
        int jhi = m; if (jhi > 23) jhi = 23;
        float s = 0.f;
        for (int j = jlo; j <= jhi; ++j)
          s += phi_tilde[j * 16 + i] * phi[(m - j) * 17 + l];
        w4[p] = s;
      }
      __syncthreads();
      float s = 0.f;
      for (int m = 0; m < 48; ++m)
        s += w4[m] * ynh[(size_t)(L_HIST - 3 - m) * 256 + p];
      val = powf(lambda_e[i], 0.25f) * powf(sigma[l], 0.25f) * s;
    }
    wvec[v * 256 + p] = val;
    return;
  }
  int idx = blockIdx.x * 256 + threadIdx.x;
  if (idx < 262144) {
    int r = idx >> 9, c = idx & 511;
    float x = A[idx];
    ushortT h = f2bf(x); ushortT l = f2bf(x - bf2f(h));
    N1h[idx] = h; N1l[idx] = l;
    T1h[c * 512 + r] = h; T1l[c * 512 + r] = l;
  } else if (idx < 262144 + 131072) {
    int i2 = idx - 262144;
    int d = i2 >> 8, c = i2 & 255;
    WTh[c * 512 + d] = f2bf(B[i2]);
  } else {
    int i2 = idx - 393216;          // < 128*8192
    int j = i2 >> 13, k = i2 & 8191;
    int tau = k >> 8, c = k & 255;
    float v = 0.f;
    if (j < 64) v = uh[(size_t)(L_HIST - 1 - (32 * j + tau)) * 256 + c];
    else if (j == 64 && tau < 16) v = uh[(size_t)(L_HIST - 1 - tau) * 256 + c];
    ushortT h = f2bf(v);
    UTh[i2] = h; UTl[i2] = f2bf(v - bf2f(h));
  }
}

// ---------------- sgemm stage A: S_{1..3} + W_{5..7} ------------------------
__global__ __launch_bounds__(512) void sgemm_a(
    const float* __restrict__ Pf2, const float* __restrict__ Qpart,
    const float* __restrict__ Rpart, float* __restrict__ Spart,
    float* __restrict__ Wpart) {
  int g = blockIdx.x;          // 0..5
  int dc = blockIdx.y;         // 0..3
  int j2 = (g < 3) ? g + 1 : g + 2;        // 1,2,3 | 5,6,7
  int plane = (g < 3) ? g : g - 3;         // T256,T512,T768
  int d0 = dc * 128;
  int m = threadIdx.x;
  __shared__ float Rs[128];
  if (threadIdx.x < 128) {
    int dd = threadIdx.x;
    float s = 0.f;
#pragma unroll
    for (int z = 0; z < 16; ++z)
      s += Qpart[((size_t)z * 512 + d0 + dd) * 128 + 8 * j2];
    for (int p = 0; p < 28; ++p)
      s += Rpart[(size_t)p * 4096 + (d0 + dd) * 8 + j2];
    Rs[dd] = s;
  }
  __syncthreads();
  float acc = 0.f;
  for (int d = 0; d < 128; ++d)
    acc += Pf2[(size_t)plane * SLc + (size_t)(d0 + d) * 512 + m] * Rs[d];
  float* dst = (g < 3) ? Spart + (size_t)((j2 - 1) * 4 + dc) * 512
                       : Wpart + (size_t)((g - 3) * 4 + dc) * 512;
  dst[m] = acc;
}

// ---------------- sgemm stage B: Svec = T1024^T (Rb_4 + W5 + W6 + W7) -------
__global__ __launch_bounds__(512) void sgemm_b(
    const float* __restrict__ Pf2, const float* __restrict__ Qpart,
    const float* __restrict__ Rpart, const float* __restrict__ Wpart,
    float* __restrict__ Svecp) {
  int dc = blockIdx.x;
  int d0 = dc * 128;
  int m = threadIdx.x;
  __shared__ float Rs[128];
  if (threadIdx.x < 128) {
    int dd = threadIdx.x;
    float s = 0.f;
#pragma unroll
    for (int z = 0; z < 16; ++z)
      s += Qpart[((size_t)z * 512 + d0 + dd) * 128 + 32];
    for (int p = 0; p < 28; ++p)
      s += Rpart[(size_t)p * 4096 + (d0 + dd) * 8 + 4];
#pragma unroll
    for (int k = 0; k < 12; ++k)
      s += Wpart[(size_t)k * 512 + d0 + dd];
    Rs[dd] = s;
  }
  __syncthreads();
  float acc = 0.f;
  for (int d = 0; d < 128; ++d)
    acc += Pf2[(size_t)3 * SLc + (size_t)(d0 + d) * 512 + m] * Rs[d];
  Svecp[(size_t)dc * 512 + m] = acc;
}

// ---------------- finalize: y_nat & pred ------------------------------------
__global__ __launch_bounds__(64) void finalize_kernel(
    const float* __restrict__ Cmat, const float* __restrict__ Qpart,
    const float* __restrict__ Rpart, const float* __restrict__ Spart,
    const float* __restrict__ Svecp,
    const float* __restrict__ yh, float* __restrict__ out) {
  int p = blockIdx.x;
  int lane = threadIdx.x;
  float a1 = 0.f, a2 = 0.f;
  for (int t = lane; t < 512; t += 64) {
    float sb = 0.f, qp = 0.f;
#pragma unroll
    for (int z = 0; z < 16; ++z) {
      sb += Qpart[((size_t)z * 512 + t) * 128 + 0];
      qp += Qpart[((size_t)z * 512 + t) * 128 + 64];
    }
    for (int q = 0; q < 28; ++q)
      sb += Rpart[(size_t)q * 4096 + t * 8];
    for (int q = 0; q < 12; ++q)
      sb += Spart[(size_t)q * 512 + t];
#pragma unroll
    for (int dc = 0; dc < 4; ++dc)
      sb += Svecp[(size_t)dc * 512 + t];
    float cv = Cmat[(size_t)p * 512 + t];
    a1 += cv * sb;
    a2 += cv * qp;
  }
  for (int off = 32; off > 0; off >>= 1) {
    a1 += __shfl_down(a1, off);
    a2 += __shfl_down(a2, off);
  }
  if (lane == 0) {
    float ynat = yh[(size_t)(L_HIST - 1) * 256 + p] - a1;
    out[p] = ynat;
    out[256 + p] = ynat + a2;
  }
}

// ---------------- host orchestration ----------------------------------------
extern "C" void kernel_launch(void* const* d_in, const int* in_sizes, int n_in,
                              void* d_out, int out_size, void* d_ws, size_t ws_size,
                              hipStream_t stream) {
  (void)in_sizes; (void)n_in; (void)out_size; (void)ws_size;
  const float* A   = (const float*)d_in[0];
  const float* B   = (const float*)d_in[1];
  const float* C   = (const float*)d_in[2];
  const float* M   = (const float*)d_in[3];
  const float* Mb  = (const float*)d_in[4];
  const float* sig = (const float*)d_in[5];
  const float* phi = (const float*)d_in[6];
  const float* lam = (const float*)d_in[7];
  const float* pt  = (const float*)d_in[8];
  const float* yh  = (const float*)d_in[9];
  const float* uh  = (const float*)d_in[10];
  const float* ynh = (const float*)d_in[11];
  float* out = (float*)d_out;
  char* base = (char*)d_ws;

  const size_t HMB = 512u * 1024u;
  const size_t SL = 512 * 512;
  ushortT* POW  = (ushortT*)base;                  // 16 slots x (hi+lo) = 16MB
  ushortT* WTh  = (ushortT*)(base + 32 * HMB);     // 8192x512  (8MB)
  ushortT* P1th = (ushortT*)(base + 48 * HMB);     // 7 x SL
  ushortT* P1tl = (ushortT*)(base + 55 * HMB);
  ushortT* P2th = (ushortT*)(base + 62 * HMB);
  ushortT* P2tl = (ushortT*)(base + 69 * HMB);
  float*   Pf1  = (float*)(base + 76 * HMB);       // 4 planes used (T32..T128)
  float*   Pf2  = (float*)(base + 90 * HMB);       // 4 planes used (T256..T1024)
  ushortT* UTh  = (ushortT*)(base + 104 * HMB);    // 128x8192 (2MB)
  ushortT* UTl  = (ushortT*)(base + 108 * HMB);
  float*   Qpart= (float*)(base + 112 * HMB);      // 16x512x128 fp32 (4MB)
  float*   Rpart= (float*)(base + 120 * HMB);      // 28x4096
  float*   Spart= Rpart + 28 * 4096;               // 12x512 used
  float*   wvec = Spart + 28 * 512;                // 306x256
  float*   Vpart= wvec + 306 * 256;                // 12x4096
  float*   Wpart= Vpart + 12 * 4096;               // 12x512
  float*   Svecp= Wpart + 12 * 512;                // 4x512

  auto ph = [&](int i) { return POW + (size_t)i * 2 * SL; };
  auto pl = [&](int i) { return POW + (size_t)i * 2 * SL + SL; };
  auto e1h = [&](int j) { return P1th + (size_t)(j - 1) * SL; };
  auto e1l = [&](int j) { return P1tl + (size_t)(j - 1) * SL; };
  auto e2h = [&](int j) { return P2th + (size_t)(j - 1) * SL; };
  auto e2l = [&](int j) { return P2tl + (size_t)(j - 1) * SL; };

  auto mkJ = [&](const ushortT* Ph, const ushortT* Qh, const ushortT* Ql,
                 ushortT* Ch, ushortT* Cl, float* Cf, int Mrows) {
    Job j; j.Ph = Ph; j.Qh = Qh; j.Ql = Ql;
    j.Ch = Ch; j.Cl = Cl; j.Cf = Cf; j.M = Mrows; j.tbase = 0; return j;
  };
  int uvoff = 0;
  auto runL = [&](Job j0, Job j1, Job j2, int nj, int qcnt, int racnt, int rbcnt,
                  int utcnt) {
    Prm p; p.j[0] = j0; p.j[1] = (nj > 1) ? j1 : j0; p.j[2] = (nj > 2) ? j2 : j0;
    p.nj = nj;
    int tb = 0;
    for (int i = 0; i < nj; ++i) { p.j[i].tbase = tb; tb += (p.j[i].M >> 6) * 8; }
    p.qbase = tb; p.rabase = tb + qcnt; p.rbbase = p.rabase + racnt;
    p.utbase = p.rbbase + rbcnt;
    p.uv0 = uvoff; uvoff += utcnt;
    p.Wt = WTh; p.Uh = UTh; p.Ul = UTl; p.Qp = Qpart;
    p.Pf1 = Pf1; p.Rp = Rpart; p.Vp = Vpart;
    p.Mt = M; p.Mbar = Mb; p.wv = wvec; p.outp = out;
    mega<<<p.utbase + utcnt, 256, 0, stream>>>(p);
  };

  // ---- init + u_t weights ----
  init_all<<<5938, 256, 0, stream>>>(A, B, uh, ph(0), pl(0), ph(1), pl(1),
                                     WTh, UTh, UTl,
                                     ynh, sig, phi, lam, pt, wvec, out);

  Job d = mkJ(ph(0), ph(1), pl(1), ph(2), pl(2), nullptr, 512); // dummy
  // ---- 10-launch chain; qgemm@L6, rgemmA@L8, rgemmB@L9; ut spread ----
  runL(mkJ(ph(0), ph(1), pl(1), ph(2), pl(2), nullptr, 512),              // N2
       mkJ(ph(1), ph(0), pl(0), ph(3), pl(3), nullptr, 512),              // T2
       mkJ(WTh, ph(0), pl(0), WTh + 256 * 512, nullptr, nullptr, 256),    // W1
       3, 0, 0, 0, 102);
  runL(mkJ(ph(2), ph(3), pl(3), ph(4), pl(4), nullptr, 512),              // N4
       mkJ(ph(3), ph(2), pl(2), ph(5), pl(5), nullptr, 512),              // T4
       mkJ(WTh, ph(2), pl(2), WTh + 512 * 512, nullptr, nullptr, 512),    // W2:4
       3, 0, 0, 0, 102);
  runL(mkJ(ph(4), ph(5), pl(5), ph(6), pl(6), nullptr, 512),              // N8
       mkJ(ph(5), ph(4), pl(4), ph(7), pl(7), nullptr, 512),              // T8
       mkJ(WTh, ph(4), pl(4), WTh + 1024 * 512, nullptr, nullptr, 1024),  // W4:8
       3, 0, 0, 0, 102);
  runL(mkJ(ph(6), ph(7), pl(7), ph(8), pl(8), nullptr, 512),              // N16
       mkJ(ph(7), ph(6), pl(6), ph(9), pl(9), nullptr, 512),              // T16
       mkJ(WTh, ph(6), pl(6), WTh + 2048 * 512, nullptr, nullptr, 2048),  // W8:16
       3, 0, 0, 0, 102);
  runL(mkJ(ph(8), ph(9), pl(9), ph(10), pl(10), nullptr, 512),            // N32
       mkJ(ph(9), ph(8), pl(8), e1h(1), e1l(1), Pf1, 512),                // T32->P1.0
       mkJ(WTh, ph(8), pl(8), WTh + 4096 * 512, nullptr, nullptr, 4096),  // W16:32
       3, 0, 0, 0, 102);
  runL(mkJ(ph(10), e1h(1), e1l(1), ph(11), pl(11), nullptr, 512),         // N64
       mkJ(e1h(1), ph(10), pl(10), e1h(2), e1l(2), Pf1 + SL, 512),        // T64->P1.1
       d, 2, 256, 0, 0, 102);                                             // + qgemm
  runL(mkJ(ph(11), e1h(2), e1l(2), ph(12), pl(12), nullptr, 512),         // N128
       mkJ(e1h(1), ph(11), pl(11), e1h(3), e1l(3), Pf1 + 2 * SL, 1024),   // T96,T128->P1.2,3
       d, 2, 0, 0, 0, 102);
  runL(mkJ(ph(12), e1h(4), e1l(4), ph(13), pl(13), nullptr, 512),         // N256
       mkJ(e1h(4), ph(12), pl(12), e2h(1), e2l(1), Pf2, 512),             // T256->P2.0
       d, 2, 0, 48, 0, 102);                                              // + rgemmA
  runL(mkJ(ph(13), e2h(1), e2l(1), ph(14), pl(14), nullptr, 512),         // N512
       mkJ(e2h(1), ph(13), pl(13), e2h(2), e2l(2), Pf2 + SL, 512),        // T512->P2.1
       d, 2, 0, 0, 32, 102);                                              // + rgemmB
  runL(mkJ(e2h(1), ph(14), pl(14), e2h(3), nullptr, Pf2 + 2 * SL, 1024),  // T768,T1024->P2.2,3
       d, d, 1, 0, 0, 0, 106);

  // ---- tails: sgemmA -> sgemmB -> finalize ----
  sgemm_a<<<dim3(6, 4), 512, 0, stream>>>(Pf2, Qpart, Rpart, Spart, Wpart);
  sgemm_b<<<4, 512, 0, stream>>>(Pf2, Qpart, Rpart, Wpart, Svecp);
  finalize_kernel<<<256, 64, 0, stream>>>(C, Qpart, Rpart, Spart, Svecp, yh, out);
}